// Round 6
// baseline (644.166 us; speedup 1.0000x reference)
//
#include <hip/hip_runtime.h>

#define KNN 20
#define NN 4096
#define NPTS 32768
#define PPW 8

using short8 = __attribute__((ext_vector_type(8))) short;
using f32x4v = __attribute__((ext_vector_type(4))) float;
using uint4v = __attribute__((ext_vector_type(4))) unsigned int;

__device__ __forceinline__ float lrelu(float x){ return x >= 0.f ? x : 0.2f*x; }
__device__ __forceinline__ unsigned short f2b(float x){
    union { float f; unsigned u; } v; v.f = x;
    unsigned r = v.u + 0x7FFFu + ((v.u >> 16) & 1u);
    return (unsigned short)(r >> 16);
}
__device__ __forceinline__ float b2f(unsigned h){
    union { unsigned u; float f; } v; v.u = h << 16; return v.f;
}
#define WSYNC() do { asm volatile("s_waitcnt lgkmcnt(0)" ::: "memory"); __builtin_amdgcn_sched_barrier(0); } while(0)

// swizzled fragment slot: fragi*1024 + ((klocal + 16*gp) ^ (5*gp))*16
__device__ __forceinline__ int fslot(int fragi, int klocal, int gp){
    return fragi*1024 + (((klocal) + ((gp)<<4)) ^ ((gp)*5))*16;
}

// ---------------- kprep: pack weight fragments + derived weights ----------------
__global__ void kprep(const float* __restrict__ weff, const float* __restrict__ wattn,
                      const float* __restrict__ wres, const float* __restrict__ wl,
                      unsigned short* __restrict__ packW, float* __restrict__ wdiff,
                      float* __restrict__ w32t, float* __restrict__ wrb,
                      float* __restrict__ rww)
{
    __shared__ float sres[4096];   // wres[o][c]
    __shared__ float sweff[4160];  // weff[c][j]
    __shared__ float scomb[2048];  // Wcomb[o][j] = sum_c wres[o][c]*weff[c][j]
    int t = threadIdx.x;
    for (int m=t; m<4096; m+=256) sres[m] = wres[m];
    for (int m=t; m<4160; m+=256) sweff[m] = weff[m];
    __syncthreads();
    for (int q=t;q<2048;q+=256){
        int c=q>>5, j=q&31;
        wdiff[q] = sweff[c*65+33+j]-sweff[c*65+j];
    }
    if (t<64) w32t[t] = sweff[t*65+32];
    for (int q=t;q<2048;q+=256){
        int o=q>>5, j=q&31;
        float a=0.f, b=0.f;
        for (int c=0;c<64;c++){
            float wr = sres[o*64+c];
            a += wr*sweff[c*65+j];
            b += wr*(sweff[c*65+33+j]-sweff[c*65+j]);
        }
        scomb[q]=a; wrb[q]=b;
    }
    if (t<64){
        float a=0.f;
        for (int c=0;c<64;c++) a += sres[t*64+c]*sweff[c*65+32];
        rww[t]=a;
    }
    __syncthreads();
    // frags 0..23: weff(4), wattn(12), wres(8)
    for (int q = t; q < 1536; q += 256){
        int f = q >> 6, l = q & 63;
        #pragma unroll
        for (int j=0;j<8;j++){
            int koff, n; float v;
            if (f < 4){ n = f*16 + (l&15); koff = 0;
                int k = koff + (j>=4?16:0) + 4*(l>>4) + (j&3);
                v = sweff[n*65 + k];
            } else if (f < 16){ int ff=f-4; n = (ff>>1)*16 + (l&15); koff = (ff&1)*32;
                int k = koff + (j>=4?16:0) + 4*(l>>4) + (j&3);
                v = wattn[n*64 + k];
            } else { int ff=f-16; n = (ff>>1)*16 + (l&15); koff = (ff&1)*32;
                int k = koff + (j>=4?16:0) + 4*(l>>4) + (j&3);
                v = sres[n*64 + k];
            }
            packW[(size_t)(f*64+l)*8 + j] = f2b(v);
        }
    }
    // frags 24..27: Wcomb (K=32); 28..31: wl (K=16 padded)
    for (int q=t;q<512;q+=256){
        int f=q>>6, l=q&63;
        int nt = f&3; bool iswl = f>=4;
        #pragma unroll
        for (int j=0;j<8;j++){
            int kdim = (j>=4?16:0)+4*(l>>4)+(j&3);
            float v;
            if (!iswl) v = scomb[(nt*16+(l&15))*32 + kdim];
            else v = (kdim<16) ? wl[(nt*16+(l&15))*16 + kdim] : 0.f;
            packW[(size_t)((24+f)*64+l)*8+j] = f2b(v);
        }
    }
}

// ---------------- K0: tables + q/base/rb GEMV + stats ----------------
__global__ void __launch_bounds__(256) k0_prep(
    const float* __restrict__ pts, const float* __restrict__ feat,
    const float* __restrict__ wq, const float* __restrict__ wpos1,
    const float* __restrict__ wefp, const float* __restrict__ wdiff,
    const float* __restrict__ wrb,
    unsigned short* __restrict__ ft16, float* __restrict__ pt4,
    unsigned short* __restrict__ qp16, float* __restrict__ pp,
    unsigned short* __restrict__ base16, float* __restrict__ bpp,
    unsigned short* __restrict__ rb16,
    float* __restrict__ qsum, float* __restrict__ qsq,
    float* __restrict__ psum, float* __restrict__ psq)
{
    __shared__ float swq[2048];
    __shared__ float swd[2048];
    __shared__ float swr[2048];
    __shared__ float red[4][64], red2[4][64];
    int tid = threadIdx.x;
    for (int m=tid;m<2048;m+=256){ swq[m]=wq[m]; swd[m]=wdiff[m]; swr[m]=wrb[m]; }
    __syncthreads();
    int r = blockIdx.x*256 + tid;
    int b = r >> 12, n = r & 4095;
    float p0 = pts[((size_t)b*3+0)*NN+n];
    float p1 = pts[((size_t)b*3+1)*NN+n];
    float p2 = pts[((size_t)b*3+2)*NN+n];
    float pm = (p0+p1+p2)*(1.f/3.f);
    *(float4*)(pt4 + (size_t)r*4) = make_float4(p0,p1,p2,pm);
    float f[32];
    #pragma unroll
    for (int c=0;c<32;c++) f[c] = feat[((size_t)b*32+c)*NN+n];
    #pragma unroll
    for (int c=0;c<32;c+=2){
        unsigned pk = (unsigned)f2b(f[c]) | ((unsigned)f2b(f[c+1])<<16);
        *(unsigned*)(ft16 + (size_t)r*32 + c) = pk;
    }
    float q[64];
    for (int o=0;o<64;o++){
        float a=0.f;
        #pragma unroll
        for (int c=0;c<32;c++) a += swq[o*32+c]*f[c];
        q[o]=a;
    }
    for (int o=0;o<64;o+=2){
        unsigned pk = (unsigned)f2b(q[o]) | ((unsigned)f2b(q[o+1])<<16);
        *(unsigned*)(qp16 + (size_t)r*64 + o) = pk;
    }
    int lane = tid & 63, wvv = tid>>6;
    for (int o=0;o<64;o++){
        float s=q[o], s2=q[o]*q[o];
        for (int d=1; d<64; d<<=1){ s += __shfl_xor(s,d); s2 += __shfl_xor(s2,d); }
        if (lane==0){ red[wvv][o]=s; red2[wvv][o]=s2; }
    }
    __syncthreads();
    if (tid<64){
        atomicAdd(qsum+tid, red[0][tid]+red[1][tid]+red[2][tid]+red[3][tid]);
        atomicAdd(qsq+tid, red2[0][tid]+red2[1][tid]+red2[2][tid]+red2[3][tid]);
    }
    for (int o=0;o<64;o++){
        float a=0.f;
        #pragma unroll
        for (int c=0;c<32;c++) a += swd[o*32+c]*f[c];
        q[o]=a;
    }
    for (int o=0;o<64;o+=2){
        unsigned pk = (unsigned)f2b(q[o]) | ((unsigned)f2b(q[o+1])<<16);
        *(unsigned*)(base16 + (size_t)r*64 + o) = pk;
    }
    // rb = f . Wrb^T
    for (int o=0;o<64;o++){
        float a=0.f;
        #pragma unroll
        for (int c=0;c<32;c++) a += swr[o*32+c]*f[c];
        q[o]=a;
    }
    for (int o=0;o<64;o+=2){
        unsigned pk = (unsigned)f2b(q[o]) | ((unsigned)f2b(q[o+1])<<16);
        *(unsigned*)(rb16 + (size_t)r*64 + o) = pk;
    }
    float pr[8];
    #pragma unroll
    for (int o=0;o<6;o++) pr[o] = wpos1[o*3]*p0 + wpos1[o*3+1]*p1 + wpos1[o*3+2]*p2;
    pr[6]=0.f; pr[7]=0.f;
    *(float4*)(pp+(size_t)r*8)   = make_float4(pr[0],pr[1],pr[2],pr[3]);
    *(float4*)(pp+(size_t)r*8+4) = make_float4(pr[4],pr[5],pr[6],pr[7]);
    __syncthreads();
    for (int o=0;o<6;o++){
        float s=pr[o], s2=pr[o]*pr[o];
        for (int d=1;d<64;d<<=1){ s += __shfl_xor(s,d); s2 += __shfl_xor(s2,d); }
        if (lane==0){ red[wvv][o]=s; red2[wvv][o]=s2; }
    }
    __syncthreads();
    if (tid<6){
        atomicAdd(psum+tid, red[0][tid]+red[1][tid]+red[2][tid]+red[3][tid]);
        atomicAdd(psq+tid, red2[0][tid]+red2[1][tid]+red2[2][tid]+red2[3][tid]);
    }
    #pragma unroll
    for (int j=0;j<6;j++)
        bpp[(size_t)r*8+j] = p0*(wefp[j*7+4]-wefp[j*7]) + p1*(wefp[j*7+5]-wefp[j*7+1])
                           + p2*(wefp[j*7+6]-wefp[j*7+2]);
    bpp[(size_t)r*8+6]=0.f; bpp[(size_t)r*8+7]=0.f;
}

// ---------------- K1: bnq / bnp params ----------------
__global__ void k1_paramsA(
    const float* __restrict__ qsum, const float* __restrict__ qsq,
    const float* __restrict__ psum, const float* __restrict__ psq,
    const float* __restrict__ gq, const float* __restrict__ bq,
    const float* __restrict__ gp, const float* __restrict__ bp,
    float* __restrict__ bnq_a, float* __restrict__ bnq_c,
    float* __restrict__ bnp_a, float* __restrict__ bnp_c)
{
    int t = threadIdx.x;
    const float inv = 1.f/32768.f;
    if (t < 64){
        float m = qsum[t]*inv; float v = qsq[t]*inv - m*m;
        float a = gq[t]*rsqrtf(v + 1e-5f);
        bnq_a[t] = a; bnq_c[t] = bq[t] - m*a;
    }
    if (t < 6){
        float m = psum[t]*inv; float v = psq[t]*inv - m*m;
        float a = gp[t]*rsqrtf(v + 1e-5f);
        bnp_a[t] = a; bnp_c[t] = bp[t] - m*a;
    }
}

// ---------------- K2: fused attention, MFMA, pipelined wave-per-point ----------------
// LDS per-wave arena 10240 B, overlaid regions:
//  R1 [0,4096):    ANB frags 0,1 (staging) -> overwritten by ATR frags 0..3 (softmax)
//  R2 [4096,8192): KFR frags 0..3 -> overwritten by A2B rows (stride 200)
#define ARENA 10240
#define R1    0
#define R2    4096
#define SFM   8192
#define SSKP  8320
#define SIDX  8960
#define YST   9600

__global__ void __launch_bounds__(256, 4) k2_main(
    const unsigned short* __restrict__ ft16, const float* __restrict__ pt4,
    const unsigned short* __restrict__ qp16, const float* __restrict__ pp,
    const unsigned short* __restrict__ base16, const float* __restrict__ bpp,
    const int* __restrict__ idx,
    const float* __restrict__ wefp, const float* __restrict__ wpos2,
    const unsigned short* __restrict__ packW, const float* __restrict__ w32t,
    const float* __restrict__ bnq_a, const float* __restrict__ bnq_c,
    const float* __restrict__ bnp_a, const float* __restrict__ bnp_c,
    unsigned short* __restrict__ yv,
    float* __restrict__ yslot, float* __restrict__ rslot)
{
    __shared__ __align__(16) char smem_[4*ARENA];
    const int tid = threadIdx.x;
    const int l = tid & 63, wv = tid >> 6;
    const int lo = l & 15, g = l >> 4;
    char* S = smem_ + wv*ARENA;
    const int srd = (l ^ (g*5))*16;

    float w2r[4][6], w32r[4], bnqa[4], bnqc[4];
    #pragma unroll
    for (int nt=0;nt<4;nt++){
        #pragma unroll
        for (int j=0;j<6;j++) w2r[nt][j] = wpos2[(nt*16+lo)*6+j];
        w32r[nt] = w32t[nt*16+lo];
        bnqa[nt] = bnq_a[nt*16+lo];
        bnqc[nt] = bnq_c[nt*16+lo];
    }
    float bnpa[6], bnpc[6];
    #pragma unroll
    for (int j=0;j<6;j++){ bnpa[j]=bnp_a[j]; bnpc[j]=bnp_c[j]; }

    float ysum=0.f, ysq=0.f;
    float racc[4]={0.f,0.f,0.f,0.f}, rsqa[4]={0.f,0.f,0.f,0.f};

    const int rbase = blockIdx.x*(4*PPW) + wv*PPW;

    *(int*)(S+SIDX+l*4)        = idx[(size_t)rbase*KNN + l];
    *(int*)(S+SIDX+(64+l)*4)   = idx[(size_t)rbase*KNN + 64 + l];
    if (l < 32) *(int*)(S+SIDX+(128+l)*4) = idx[(size_t)rbase*KNN + 128 + l];
    WSYNC();

    uint2 ng0, ng1; uint2 ng2 = make_uint2(0u,0u); float4 ngp4 = make_float4(0,0,0,0);
    unsigned short nqr[4], nbr[4];
    float nppr[6], nbppr[6];
    float xqv[4], basev[4], sp[6];

#define ISSUE(pi_) { \
    int sb = (pi_)*KNN*4; size_t rr = (size_t)(rbase + (pi_)); \
    int i0 = *(const int*)(S+SIDX+sb+(l>>3)*4); \
    int i1 = *(const int*)(S+SIDX+sb+(8+(l>>3))*4); \
    ng0 = *(const uint2*)(ft16 + (size_t)i0*32 + (l&7)*4); \
    ng1 = *(const uint2*)(ft16 + (size_t)i1*32 + (l&7)*4); \
    if (l < 32){ int i2 = *(const int*)(S+SIDX+sb+(16+(l>>3))*4); \
                 ng2 = *(const uint2*)(ft16 + (size_t)i2*32 + (l&7)*4); } \
    if (l < KNN){ int ip = *(const int*)(S+SIDX+sb+l*4); \
                  ngp4 = *(const float4*)(pt4 + (size_t)ip*4); } \
    _Pragma("unroll") for (int nt=0;nt<4;nt++){ \
        nqr[nt] = qp16[rr*64 + nt*16+lo]; nbr[nt] = base16[rr*64 + nt*16+lo]; } \
    _Pragma("unroll") for (int j=0;j<6;j++){ nppr[j] = pp[rr*8+j]; nbppr[j] = bpp[rr*8+j]; } \
    __builtin_amdgcn_sched_barrier(0); \
}

#define STAGE() { \
    float s0 = b2f(ng0.x&0xffffu)+b2f(ng0.x>>16)+b2f(ng0.y&0xffffu)+b2f(ng0.y>>16); \
    float s1 = b2f(ng1.x&0xffffu)+b2f(ng1.x>>16)+b2f(ng1.y&0xffffu)+b2f(ng1.y>>16); \
    float s2 = b2f(ng2.x&0xffffu)+b2f(ng2.x>>16)+b2f(ng2.y&0xffffu)+b2f(ng2.y>>16); \
    s0 += __shfl_xor(s0,1); s0 += __shfl_xor(s0,2); s0 += __shfl_xor(s0,4); \
    s1 += __shfl_xor(s1,1); s1 += __shfl_xor(s1,2); s1 += __shfl_xor(s1,4); \
    s2 += __shfl_xor(s2,1); s2 += __shfl_xor(s2,2); s2 += __shfl_xor(s2,4); \
    if ((l&7)==0){ \
        *(float*)(S+SFM+(l>>3)*4) = s0*(1.f/32.f); \
        *(float*)(S+SFM+(8+(l>>3))*4) = s1*(1.f/32.f); \
        if (l < 32) *(float*)(S+SFM+(16+(l>>3))*4) = s2*(1.f/32.f); \
    } \
    { int kk = l>>3, gp_ = l&3, jb = ((l>>2)&1)*8; \
      *(uint2*)(S + R1 + fslot(0, kk, gp_) + jb) = ng0; \
      *(uint2*)(S + R1 + fslot(0, 8+kk, gp_) + jb) = ng1; \
      if (l < 32) *(uint2*)(S + R1 + fslot(1, kk, gp_) + jb) = ng2; } \
    if (l < KNN){ \
        _Pragma("unroll") for (int j=0;j<6;j++){ \
            float v = nbppr[j] + wefp[j*7]*ngp4.x + wefp[j*7+1]*ngp4.y \
                    + wefp[j*7+2]*ngp4.z + wefp[j*7+3]*ngp4.w; \
            *(float*)(S+SSKP+(l*8+j)*4) = v; } } \
    _Pragma("unroll") for (int nt=0;nt<4;nt++){ \
        xqv[nt] = lrelu(bnqa[nt]*b2f(nqr[nt]) + bnqc[nt]); \
        basev[nt] = b2f(nbr[nt]); } \
    _Pragma("unroll") for (int j=0;j<6;j++) sp[j] = lrelu(bnpa[j]*nppr[j] + bnpc[j]); \
    WSYNC(); \
}

    ISSUE(0);
    STAGE();

    for (int pi=0; pi<PPW; pi++){
        const size_t r = (size_t)(rbase + pi);
        if (pi < PPW-1) ISSUE(pi+1);

        // ---- MFMA-1: kf_raw[k][c] (reads R1 ANB frags) ----
        f32x4v C1[2][4];
        #pragma unroll
        for (int mt=0;mt<2;mt++)
            #pragma unroll
            for (int nt=0;nt<4;nt++)
                #pragma unroll
                for (int i=0;i<4;i++) C1[mt][nt][i] = 0.f;
        short8 Af0 = *(const short8*)(S + R1 + 0*1024 + srd);
        short8 Af1 = *(const short8*)(S + R1 + 1*1024 + srd);
        #pragma unroll
        for (int nt=0;nt<4;nt++){
            short8 Bf = *(const short8*)(packW + (size_t)(nt*64 + l)*8);
            C1[0][nt] = __builtin_amdgcn_mfma_f32_16x16x32_bf16(Af0, Bf, C1[0][nt], 0, 0, 0);
            C1[1][nt] = __builtin_amdgcn_mfma_f32_16x16x32_bf16(Af1, Bf, C1[1][nt], 0, 0, 0);
        }
        // ---- epilogue: kf frags -> R2, attn logits ----
        #pragma unroll
        for (int mt=0;mt<2;mt++){
            #pragma unroll
            for (int i=0;i<4;i++){
                int k = mt*16 + g*4 + i;
                bool valid = (k < KNN);
                int kk = valid ? k : 0;
                float fmk = *(const float*)(S+SFM+kk*4);
                float sk[6];
                #pragma unroll
                for (int j=0;j<6;j++) sk[j] = *(const float*)(S+SSKP+(kk*8+j)*4);
                #pragma unroll
                for (int nt=0;nt<4;nt++){
                    float kf = C1[mt][nt][i] + basev[nt] + w32r[nt]*fmk;
                    if (valid){
                        int fa = fslot(mt*2+(nt>>1), g*4+i, lo>>2) + ((nt&1)*4 + (lo&3))*2;
                        *(unsigned short*)(S + R2 + fa) = f2b(kf);
                    }
                    float pos = 0.f;
                    #pragma unroll
                    for (int j=0;j<6;j++) pos += (sp[j]-sk[j])*w2r[nt][j];
                    C1[mt][nt][i] = valid ? (xqv[nt] - kf + pos)*0.125f : -1e30f;
                }
            }
        }
        // ---- softmax over k per channel; attn frags -> R1 ----
        #pragma unroll
        for (int nt=0;nt<4;nt++){
            float mx = -1e30f;
            #pragma unroll
            for (int mt=0;mt<2;mt++)
                #pragma unroll
                for (int i=0;i<4;i++) mx = fmaxf(mx, C1[mt][nt][i]);
            mx = fmaxf(mx, __shfl_xor(mx,16));
            mx = fmaxf(mx, __shfl_xor(mx,32));
            float sm = 0.f;
            #pragma unroll
            for (int mt=0;mt<2;mt++)
                #pragma unroll
                for (int i=0;i<4;i++){ float e = __expf(C1[mt][nt][i]-mx); C1[mt][nt][i]=e; sm += e; }
            sm += __shfl_xor(sm,16);
            sm += __shfl_xor(sm,32);
            float inv = 1.f/sm;
            #pragma unroll
            for (int mt=0;mt<2;mt++)
                #pragma unroll
                for (int i=0;i<4;i++){
                    int k = mt*16 + g*4 + i;
                    if (k < KNN){
                        int fa = fslot(mt*2+(nt>>1), g*4+i, lo>>2) + ((nt&1)*4 + (lo&3))*2;
                        *(unsigned short*)(S + R1 + fa) = f2b(C1[mt][nt][i]*inv);
                    }
                }
        }
        WSYNC();
        // ---- MFMA-3 (reads R2 KFR) + MFMA-2 (reads R1 ATR): one cluster ----
        short8 Ak[2][2], Aa[2][2];
        #pragma unroll
        for (int mt=0;mt<2;mt++)
            #pragma unroll
            for (int s=0;s<2;s++){
                Ak[mt][s] = *(const short8*)(S + R2 + (mt*2+s)*1024 + srd);
                Aa[mt][s] = *(const short8*)(S + R1 + (mt*2+s)*1024 + srd);
            }
        f32x4v C3[2][4];
        #pragma unroll
        for (int mt=0;mt<2;mt++)
            #pragma unroll
            for (int nt=0;nt<4;nt++)
                #pragma unroll
                for (int i=0;i<4;i++) C3[mt][nt][i] = 0.f;
        #pragma unroll
        for (int nt=0;nt<4;nt++){
            #pragma unroll
            for (int s=0;s<2;s++){
                short8 Bf = *(const short8*)(packW + (size_t)((16+nt*2+s)*64 + l)*8);
                #pragma unroll
                for (int mt=0;mt<2;mt++)
                    C3[mt][nt] = __builtin_amdgcn_mfma_f32_16x16x32_bf16(Ak[mt][s], Bf, C3[mt][nt], 0, 0, 0);
            }
        }
        f32x4v C2[2][6];
        #pragma unroll
        for (int mt=0;mt<2;mt++)
            #pragma unroll
            for (int nt=0;nt<6;nt++)
                #pragma unroll
                for (int i=0;i<4;i++) C2[mt][nt][i] = 0.f;
        #pragma unroll
        for (int nt=0;nt<6;nt++){
            #pragma unroll
            for (int s=0;s<2;s++){
                short8 Bf = *(const short8*)(packW + (size_t)((4+nt*2+s)*64 + l)*8);
                #pragma unroll
                for (int mt=0;mt<2;mt++)
                    C2[mt][nt] = __builtin_amdgcn_mfma_f32_16x16x32_bf16(Aa[mt][s], Bf, C2[mt][nt], 0, 0, 0);
            }
        }
        // ---- rf stats from C3 (regs only) ----
        #pragma unroll
        for (int mt=0;mt<2;mt++)
            #pragma unroll
            for (int i=0;i<4;i++){
                int k = mt*16 + g*4 + i;
                if (k < KNN){
                    #pragma unroll
                    for (int nt=0;nt<4;nt++){
                        float v = C3[mt][nt][i];
                        racc[nt] += v; rsqa[nt] += v*v;
                    }
                }
            }
        // ---- A2B rows -> R2 (stride 200) ----
        #pragma unroll
        for (int mt=0;mt<2;mt++)
            #pragma unroll
            for (int nt=0;nt<6;nt++)
                #pragma unroll
                for (int i=0;i<4;i++){
                    int k = mt*16 + g*4 + i;
                    if (k < KNN)
                        *(unsigned short*)(S + R2 + k*200 + (nt*16+lo)*2) = f2b(C2[mt][nt][i]);
                }
        WSYNC();
        // ---- y[k][h] ----
        #pragma unroll
        for (int it=0; it<5; it++){
            int kq = it*4 + g;
            const char* row = S + R2 + kq*200 + lo*12;
            unsigned d0 = *(const unsigned*)(row);
            unsigned d1 = *(const unsigned*)(row+4);
            unsigned d2 = *(const unsigned*)(row+8);
            float yval = b2f(d0&0xffffu) * (*(const float*)(S+SSKP+(kq*8+0)*4))
                       + b2f(d0>>16)    * (*(const float*)(S+SSKP+(kq*8+1)*4))
                       + b2f(d1&0xffffu)* (*(const float*)(S+SSKP+(kq*8+2)*4))
                       + b2f(d1>>16)    * (*(const float*)(S+SSKP+(kq*8+3)*4))
                       + b2f(d2&0xffffu)* (*(const float*)(S+SSKP+(kq*8+4)*4))
                       + b2f(d2>>16)    * (*(const float*)(S+SSKP+(kq*8+5)*4));
            *(unsigned short*)(S + YST + kq*32 + lo*2) = f2b(yval);
            ysum += yval; ysq += yval*yval;
        }
        WSYNC();
        // ---- coalesced yv store ----
        if (l < 40){
            uint4v v = *(const uint4v*)(S + YST + l*16);
            *(uint4v*)((char*)yv + r*640 + l*16) = v;
        }
        if (pi < PPW-1) STAGE();
    }
    // ---- stats reduce + atomics ----
    ysum += __shfl_xor(ysum,16); ysum += __shfl_xor(ysum,32);
    ysq  += __shfl_xor(ysq,16);  ysq  += __shfl_xor(ysq,32);
    #pragma unroll
    for (int nt=0;nt<4;nt++){
        racc[nt] += __shfl_xor(racc[nt],16); racc[nt] += __shfl_xor(racc[nt],32);
        rsqa[nt] += __shfl_xor(rsqa[nt],16); rsqa[nt] += __shfl_xor(rsqa[nt],32);
    }
    int slot = (blockIdx.x*4 + wv) & 63;
    if (l < 16){
        atomicAdd(yslot + slot*32 + l, ysum);
        #pragma unroll
        for (int nt=0;nt<4;nt++) atomicAdd(rslot + slot*128 + nt*16 + l, racc[nt]);
    } else if (l < 32){
        atomicAdd(yslot + slot*32 + 16 + lo, ysq);
        #pragma unroll
        for (int nt=0;nt<4;nt++) atomicAdd(rslot + slot*128 + 64 + nt*16 + lo, rsqa[nt]);
    }
#undef ISSUE
#undef STAGE
}

// ---------------- K3: bn1 (y) + bnres params ----------------
__global__ void k3_paramsB(
    const float* __restrict__ yslot, const float* __restrict__ rslot,
    const float* __restrict__ g1, const float* __restrict__ b1,
    const float* __restrict__ gr, const float* __restrict__ br,
    float* __restrict__ bn1_a, float* __restrict__ bn1_c,
    float* __restrict__ bnr_a, float* __restrict__ bnr_c)
{
    __shared__ float sy[32];
    __shared__ float sr[128];
    int t = threadIdx.x; // 128
    float s1 = 0.f;
    if (t < 32){ for (int i=0;i<64;i++) s1 += yslot[(size_t)i*32+t]; }
    float s2 = 0.f;
    for (int i=0;i<64;i++) s2 += rslot[(size_t)i*128+t];
    if (t < 32) sy[t] = s1;
    sr[t] = s2;
    __syncthreads();
    const float inv = 1.f/655360.f;
    if (t < 16){
        float m = sy[t]*inv; float v = sy[16+t]*inv - m*m;
        float a = g1[t]*rsqrtf(v + 1e-5f);
        bn1_a[t] = a; bn1_c[t] = b1[t] - m*a;
    }
    if (t < 64){
        float m = sr[t]*inv; float v = sr[64+t]*inv - m*m;
        float a = gr[t]*rsqrtf(v + 1e-5f);
        bnr_a[t] = a; bnr_c[t] = br[t] - m*a;
    }
}

// ---------------- K4: lin stats via second-moment MFMA ----------------
__global__ void __launch_bounds__(256) k4_linstats(
    const unsigned short* __restrict__ yv,
    const float* __restrict__ bn1_a, const float* __restrict__ bn1_c,
    float* __restrict__ Mslot, float* __restrict__ Sslot)
{
    __shared__ __align__(16) char lds[4*1024];
    const int tid = threadIdx.x, l = tid & 63, wvv = tid >> 6;
    const int lo = l & 15, g = l >> 4;
    char* L = lds + wvv*1024;
    const int h0 = (l&1)*8;
    float a8[8], c8[8];
    #pragma unroll
    for (int j=0;j<8;j++){ a8[j]=bn1_a[h0+j]; c8[j]=bn1_c[h0+j]; }
    short8 ones;
    #pragma unroll
    for (int j=0;j<8;j++) ones[j] = (short)0x3F80;
    f32x4v Macc, Sacc;
    #pragma unroll
    for (int i=0;i<4;i++){ Macc[i]=0.f; Sacc[i]=0.f; }
    const int waveid = blockIdx.x*4 + wvv;
    for (int it=0; it<5; it++){
        size_t s0 = ((size_t)waveid*5 + it)*32;
        uint4 v = *(const uint4*)(yv + s0*16 + l*8);
        unsigned short e0 = v.x&0xffffu, e1 = v.x>>16, e2 = v.y&0xffffu, e3 = v.y>>16;
        unsigned short e4 = v.z&0xffffu, e5 = v.z>>16, e6 = v.w&0xffffu, e7 = v.w>>16;
        float y0 = lrelu(a8[0]*b2f(e0)+c8[0]), y1 = lrelu(a8[1]*b2f(e1)+c8[1]);
        float y2_ = lrelu(a8[2]*b2f(e2)+c8[2]), y3 = lrelu(a8[3]*b2f(e3)+c8[3]);
        float y4 = lrelu(a8[4]*b2f(e4)+c8[4]), y5 = lrelu(a8[5]*b2f(e5)+c8[5]);
        float y6 = lrelu(a8[6]*b2f(e6)+c8[6]), y7 = lrelu(a8[7]*b2f(e7)+c8[7]);
        uint4 o;
        o.x = (unsigned)f2b(y0) | ((unsigned)f2b(y1)<<16);
        o.y = (unsigned)f2b(y2_)| ((unsigned)f2b(y3)<<16);
        o.z = (unsigned)f2b(y4) | ((unsigned)f2b(y5)<<16);
        o.w = (unsigned)f2b(y6) | ((unsigned)f2b(y7)<<16);
        *(uint4*)(L + l*16) = o;
        WSYNC();
        short8 Af;
        #pragma unroll
        for (int j=0;j<8;j++){
            int s = 4*g + (j&3) + ((j>=4)?16:0);
            Af[j] = *(const short*)(L + s*32 + lo*2);
        }
        WSYNC();
        Macc = __builtin_amdgcn_mfma_f32_16x16x32_bf16(Af, Af, Macc, 0, 0, 0);
        Sacc = __builtin_amdgcn_mfma_f32_16x16x32_bf16(ones, Af, Sacc, 0, 0, 0);
    }
    float* Ms = Mslot + (size_t)(waveid&15)*256;
    #pragma unroll
    for (int i=0;i<4;i++) atomicAdd(Ms + (g*4+i)*16 + lo, Macc[i]);
    if (l < 16) atomicAdd(Sslot + (size_t)(waveid&15)*16 + lo, Sacc[0]);
}

// ---------------- K5: bnlin params from M/S ----------------
__global__ void k5_paramsC(
    const float* __restrict__ Mslot, const float* __restrict__ Sslot,
    const float* __restrict__ wl,
    const float* __restrict__ gl, const float* __restrict__ bl,
    float* __restrict__ bnl_a, float* __restrict__ bnl_c)
{
    __shared__ float Ms[256], Ss[16];
    int t = threadIdx.x; // 256
    float m = 0.f;
    for (int i=0;i<16;i++) m += Mslot[(size_t)i*256+t];
    Ms[t] = m;
    if (t < 16){
        float s = 0.f;
        for (int i=0;i<16;i++) s += Sslot[(size_t)i*16+t];
        Ss[t] = s;
    }
    __syncthreads();
    if (t < 64){
        float w[16];
        #pragma unroll
        for (int h=0;h<16;h++) w[h] = wl[t*16+h];
        float lsum = 0.f;
        #pragma unroll
        for (int h=0;h<16;h++) lsum += w[h]*Ss[h];
        float lsq = 0.f;
        for (int h1=0;h1<16;h1++){
            float acc = 0.f;
            #pragma unroll
            for (int h2=0;h2<16;h2++) acc += Ms[h1*16+h2]*w[h2];
            lsq += w[h1]*acc;
        }
        const float inv = 1.f/655360.f;
        float mean = lsum*inv; float var = lsq*inv - mean*mean;
        float a = gl[t]*rsqrtf(var + 1e-5f);
        bnl_a[t] = a; bnl_c[t] = bl[t] - mean*a;
    }
}

// ---------------- K6: recompute rv + lv, combine + max over k ----------------
#define ARENA6 2848
#define SFM6 2048
#define SIDX6 2176

__global__ void __launch_bounds__(256) k6_final(
    const unsigned short* __restrict__ ft16, const unsigned short* __restrict__ yv,
    const int* __restrict__ idx, const unsigned short* __restrict__ rb16,
    const unsigned short* __restrict__ packW, const float* __restrict__ rww,
    const float* __restrict__ bn1_a, const float* __restrict__ bn1_c,
    const float* __restrict__ bnl_a, const float* __restrict__ bnl_c,
    const float* __restrict__ bnr_a, const float* __restrict__ bnr_c,
    float* __restrict__ out)
{
    __shared__ __align__(16) char smem_[4*ARENA6];
    __shared__ float sval[64*36];
    const int tid = threadIdx.x;
    const int l = tid & 63, wv = tid >> 6;
    const int lo = l & 15, g = l >> 4;
    char* S = smem_ + wv*ARENA6;
    const int srd = (l ^ (g*5))*16;

    short8 Bc[4], Bl[4];
    #pragma unroll
    for (int nt=0;nt<4;nt++){
        Bc[nt] = *(const short8*)(packW + (size_t)((24+nt)*64+l)*8);
        Bl[nt] = *(const short8*)(packW + (size_t)((28+nt)*64+l)*8);
    }
    float4 b1a = *(const float4*)(bn1_a + 4*g);
    float4 b1c = *(const float4*)(bn1_c + 4*g);
    float la[4], lc[4], ra[4], rc[4], rwv[4];
    #pragma unroll
    for (int nt=0;nt<4;nt++){
        int o = nt*16+lo;
        la[nt]=bnl_a[o]; lc[nt]=bnl_c[o]; ra[nt]=bnr_a[o]; rc[nt]=bnr_c[o]; rwv[nt]=rww[o];
    }
    const int rbase = blockIdx.x*32 + wv*8;
    *(int*)(S+SIDX6+l*4)      = idx[(size_t)rbase*KNN + l];
    *(int*)(S+SIDX6+(64+l)*4) = idx[(size_t)rbase*KNN + 64 + l];
    if (l < 32) *(int*)(S+SIDX6+(128+l)*4) = idx[(size_t)rbase*KNN + 128 + l];
    WSYNC();

    uint2 ng0, ng1; uint2 ng2 = make_uint2(0u,0u);
    uint2 ylo_, yhi_; unsigned short rbr[4];
    short8 AlyA, AlyB; float rbv[4];

#define ISSUE6(pi_) { \
    int sb = (pi_)*KNN*4; size_t rr = (size_t)(rbase + (pi_)); \
    int i0 = *(const int*)(S+SIDX6+sb+(l>>3)*4); \
    int i1 = *(const int*)(S+SIDX6+sb+(8+(l>>3))*4); \
    ng0 = *(const uint2*)(ft16 + (size_t)i0*32 + (l&7)*4); \
    ng1 = *(const uint2*)(ft16 + (size_t)i1*32 + (l&7)*4); \
    if (l < 32){ int i2 = *(const int*)(S+SIDX6+sb+(16+(l>>3))*4); \
                 ng2 = *(const uint2*)(ft16 + (size_t)i2*32 + (l&7)*4); } \
    ylo_ = *(const uint2*)(yv + rr*320 + (l&15)*16 + g*4); \
    yhi_ = make_uint2(0u,0u); \
    if (lo < 4) yhi_ = *(const uint2*)(yv + rr*320 + (16+(l&15))*16 + g*4); \
    _Pragma("unroll") for (int nt=0;nt<4;nt++) rbr[nt] = rb16[rr*64 + nt*16+lo]; \
    __builtin_amdgcn_sched_barrier(0); \
}

#define STAGE6() { \
    float s0 = b2f(ng0.x&0xffffu)+b2f(ng0.x>>16)+b2f(ng0.y&0xffffu)+b2f(ng0.y>>16); \
    float s1 = b2f(ng1.x&0xffffu)+b2f(ng1.x>>16)+b2f(ng1.y&0xffffu)+b2f(ng1.y>>16); \
    float s2 = b2f(ng2.x&0xffffu)+b2f(ng2.x>>16)+b2f(ng2.y&0xffffu)+b2f(ng2.y>>16); \
    s0 += __shfl_xor(s0,1); s0 += __shfl_xor(s0,2); s0 += __shfl_xor(s0,4); \
    s1 += __shfl_xor(s1,1); s1 += __shfl_xor(s1,2); s1 += __shfl_xor(s1,4); \
    s2 += __shfl_xor(s2,1); s2 += __shfl_xor(s2,2); s2 += __shfl_xor(s2,4); \
    if ((l&7)==0){ \
        *(float*)(S+SFM6+(l>>3)*4) = s0*(1.f/32.f); \
        *(float*)(S+SFM6+(8+(l>>3))*4) = s1*(1.f/32.f); \
        if (l < 32) *(float*)(S+SFM6+(16+(l>>3))*4) = s2*(1.f/32.f); \
    } \
    { int kk = l>>3, gp_ = l&3, jb = ((l>>2)&1)*8; \
      *(uint2*)(S + fslot(0, kk, gp_) + jb) = ng0; \
      *(uint2*)(S + fslot(0, 8+kk, gp_) + jb) = ng1; \
      if (l < 32) *(uint2*)(S + fslot(1, kk, gp_) + jb) = ng2; } \
    { float t0 = lrelu(b1a.x*b2f(ylo_.x&0xffffu)+b1c.x); \
      float t1 = lrelu(b1a.y*b2f(ylo_.x>>16)+b1c.y); \
      float t2 = lrelu(b1a.z*b2f(ylo_.y&0xffffu)+b1c.z); \
      float t3 = lrelu(b1a.w*b2f(ylo_.y>>16)+b1c.w); \
      AlyA[0]=(short)f2b(t0); AlyA[1]=(short)f2b(t1); AlyA[2]=(short)f2b(t2); AlyA[3]=(short)f2b(t3); \
      AlyA[4]=0; AlyA[5]=0; AlyA[6]=0; AlyA[7]=0; \
      t0 = lrelu(b1a.x*b2f(yhi_.x&0xffffu)+b1c.x); \
      t1 = lrelu(b1a.y*b2f(yhi_.x>>16)+b1c.y); \
      t2 = lrelu(b1a.z*b2f(yhi_.y&0xffffu)+b1c.z); \
      t3 = lrelu(b1a.w*b2f(yhi_.y>>16)+b1c.w); \
      AlyB[0]=(short)f2b(t0); AlyB[1]=(short)f2b(t1); AlyB[2]=(short)f2b(t2); AlyB[3]=(short)f2b(t3); \
      AlyB[4]=0; AlyB[5]=0; AlyB[6]=0; AlyB[7]=0; } \
    _Pragma("unroll") for (int nt=0;nt<4;nt++) rbv[nt] = b2f(rbr[nt]); \
    WSYNC(); \
}

    ISSUE6(0);
    STAGE6();

    for (int pi=0; pi<8; pi++){
        if (pi < 7) ISSUE6(pi+1);
        short8 Af0 = *(const short8*)(S + 0*1024 + srd);
        short8 Af1 = *(const short8*)(S + 1*1024 + srd);
        f32x4v Crv[2][4], Clv[2][4];
        #pragma unroll
        for (int mt=0;mt<2;mt++)
            #pragma unroll
            for (int nt=0;nt<4;nt++)
                #pragma unroll
                for (int i=0;i<4;i++){ Crv[mt][nt][i]=0.f; Clv[mt][nt][i]=0.f; }
        #pragma unroll
        for (int nt=0;nt<4;nt++){
            Crv[0][nt] = __builtin_amdgcn_mfma_f32_16x16x32_bf16(Af0, Bc[nt], Crv[0][nt], 0, 0, 0);
            Crv[1][nt] = __builtin_amdgcn_mfma_f32_16x16x32_bf16(Af1, Bc[nt], Crv[1][nt], 0, 0, 0);
            Clv[0][nt] = __builtin_amdgcn_mfma_f32_16x16x32_bf16(AlyA, Bl[nt], Clv[0][nt], 0, 0, 0);
            Clv[1][nt] = __builtin_amdgcn_mfma_f32_16x16x32_bf16(AlyB, Bl[nt], Clv[1][nt], 0, 0, 0);
        }
        float vmax[4] = {-1e30f,-1e30f,-1e30f,-1e30f};
        #pragma unroll
        for (int mt=0;mt<2;mt++)
            #pragma unroll
            for (int i=0;i<4;i++){
                int k = mt*16 + g*4 + i;
                if (k < KNN){
                    float fmk = *(const float*)(S+SFM6+k*4);
                    #pragma unroll
                    for (int nt=0;nt<4;nt++){
                        float rv = Crv[mt][nt][i] + rbv[nt] + rwv[nt]*fmk;
                        float lv = Clv[mt][nt][i];
                        float val = lrelu(la[nt]*lv + lc[nt] + ra[nt]*rv + rc[nt]);
                        vmax[nt] = fmaxf(vmax[nt], val);
                    }
                }
            }
        #pragma unroll
        for (int nt=0;nt<4;nt++){
            vmax[nt] = fmaxf(vmax[nt], __shfl_xor(vmax[nt],16));
            vmax[nt] = fmaxf(vmax[nt], __shfl_xor(vmax[nt],32));
        }
        if (l < 16){
            #pragma unroll
            for (int nt=0;nt<4;nt++)
                sval[(nt*16+lo)*36 + wv*8 + pi] = vmax[nt];
        }
        if (pi < 7) STAGE6();
    }
    __syncthreads();
    // cooperative output write: 64 o x 32 pts, full 128B lines
    {
        int o = tid >> 2, seg = tid & 3;
        float4 v0 = *(const float4*)(sval + o*36 + seg*8);
        float4 v1 = *(const float4*)(sval + o*36 + seg*8 + 4);
        size_t base = ((size_t)(blockIdx.x>>7)*64 + o)*NN + (blockIdx.x&127)*32 + seg*8;
        *(float4*)(out + base) = v0;
        *(float4*)(out + base + 4) = v1;
    }
#undef ISSUE6
#undef STAGE6
}

extern "C" void kernel_launch(void* const* d_in, const int* in_sizes, int n_in,
                              void* d_out, int out_size, void* d_ws, size_t ws_size,
                              hipStream_t stream)
{
    const float* pts   = (const float*)d_in[0];
    const float* feat  = (const float*)d_in[1];
    const int*   idx   = (const int*)d_in[2];
    const float* wefp  = (const float*)d_in[3];
    const float* weff  = (const float*)d_in[4];
    const float* wq    = (const float*)d_in[5];
    const float* gq    = (const float*)d_in[6];
    const float* bq    = (const float*)d_in[7];
    const float* wpos1 = (const float*)d_in[8];
    const float* gp    = (const float*)d_in[9];
    const float* bp    = (const float*)d_in[10];
    const float* wpos2 = (const float*)d_in[11];
    const float* wattn = (const float*)d_in[12];
    const float* g1    = (const float*)d_in[13];
    const float* b1    = (const float*)d_in[14];
    const float* wl    = (const float*)d_in[15];
    const float* gl    = (const float*)d_in[16];
    const float* bl    = (const float*)d_in[17];
    const float* wres  = (const float*)d_in[18];
    const float* gr    = (const float*)d_in[19];
    const float* br    = (const float*)d_in[20];
    float* out = (float*)d_out;

    char* ws = (char*)d_ws;
    size_t o_ft16 = 0;
    size_t o_pt4  = o_ft16 + (size_t)NPTS*64;
    size_t o_qp16 = o_pt4  + (size_t)NPTS*16;
    size_t o_pp   = o_qp16 + (size_t)NPTS*128;
    size_t o_b16  = o_pp   + (size_t)NPTS*32;
    size_t o_bpp  = o_b16  + (size_t)NPTS*128;
    size_t o_rb16 = o_bpp  + (size_t)NPTS*32;
    size_t o_packW= o_rb16 + (size_t)NPTS*128;
    size_t o_wdiff= o_packW + 32*512*2;
    size_t o_wrb  = o_wdiff + 2048*4;
    size_t o_rw   = o_wrb   + 2048*4;
    size_t o_w32  = o_rw    + 64*4;
    size_t o_st   = o_w32   + 64*4;
    size_t o_qsum  = o_st;
    size_t o_qsq   = o_qsum + 64*4;
    size_t o_psum  = o_qsq  + 64*4;
    size_t o_psq   = o_psum + 8*4;
    size_t o_yslot = o_psq  + 8*4;
    size_t o_rslot = o_yslot + (size_t)64*32*4;
    size_t o_mslot = o_rslot + (size_t)64*128*4;
    size_t o_sslot = o_mslot + (size_t)16*256*4;
    size_t zero_bytes = (o_sslot + (size_t)16*16*4) - o_st;
    size_t o_par   = o_st + zero_bytes;
    size_t o_bnq_a = o_par;
    size_t o_bnq_c = o_bnq_a + 64*4;
    size_t o_bnp_a = o_bnq_c + 64*4;
    size_t o_bnp_c = o_bnp_a + 8*4;
    size_t o_bn1_a = o_bnp_c + 8*4;
    size_t o_bn1_c = o_bn1_a + 16*4;
    size_t o_bnl_a = o_bn1_c + 16*4;
    size_t o_bnl_c = o_bnl_a + 64*4;
    size_t o_bnr_a = o_bnl_c + 64*4;
    size_t o_bnr_c = o_bnr_a + 64*4;
    size_t o_yv = (o_bnr_c + 64*4 + 255) & ~(size_t)255;

    unsigned short* ft16 = (unsigned short*)(ws + o_ft16);
    float* pt4  = (float*)(ws + o_pt4);
    unsigned short* qp16 = (unsigned short*)(ws + o_qp16);
    float* ppb  = (float*)(ws + o_pp);
    unsigned short* b16p = (unsigned short*)(ws + o_b16);
    float* bppb = (float*)(ws + o_bpp);
    unsigned short* rb16 = (unsigned short*)(ws + o_rb16);
    unsigned short* packW = (unsigned short*)(ws + o_packW);
    float* wdiff= (float*)(ws + o_wdiff);
    float* wrb  = (float*)(ws + o_wrb);
    float* rww  = (float*)(ws + o_rw);
    float* w32t = (float*)(ws + o_w32);
    float* qsum = (float*)(ws + o_qsum);
    float* qsq  = (float*)(ws + o_qsq);
    float* psum = (float*)(ws + o_psum);
    float* psq  = (float*)(ws + o_psq);
    float* yslot= (float*)(ws + o_yslot);
    float* rslot= (float*)(ws + o_rslot);
    float* Mslot= (float*)(ws + o_mslot);
    float* Sslot= (float*)(ws + o_sslot);
    float* bnq_a= (float*)(ws + o_bnq_a);
    float* bnq_c= (float*)(ws + o_bnq_c);
    float* bnp_a= (float*)(ws + o_bnp_a);
    float* bnp_c= (float*)(ws + o_bnp_c);
    float* bn1_a= (float*)(ws + o_bn1_a);
    float* bn1_c= (float*)(ws + o_bn1_c);
    float* bnl_a= (float*)(ws + o_bnl_a);
    float* bnl_c= (float*)(ws + o_bnl_c);
    float* bnr_a= (float*)(ws + o_bnr_a);
    float* bnr_c= (float*)(ws + o_bnr_c);
    unsigned short* yvp = (unsigned short*)(ws + o_yv);

    (void)hipMemsetAsync(ws + o_st, 0, zero_bytes, stream);

    kprep<<<1, 256, 0, stream>>>(weff, wattn, wres, wl, packW, wdiff, w32t, wrb, rww);
    k0_prep<<<128, 256, 0, stream>>>(pts, feat, wq, wpos1, wefp, wdiff, wrb,
                                     ft16, pt4, qp16, ppb, b16p, bppb, rb16,
                                     qsum, qsq, psum, psq);
    k1_paramsA<<<1, 64, 0, stream>>>(qsum, qsq, psum, psq, gq, bq, gp, bp,
                                     bnq_a, bnq_c, bnp_a, bnp_c);
    k2_main<<<NPTS/(4*PPW), 256, 0, stream>>>(ft16, pt4, qp16, ppb, b16p, bppb, idx,
                                     wefp, wpos2, packW, w32t,
                                     bnq_a, bnq_c, bnp_a, bnp_c,
                                     yvp, yslot, rslot);
    k3_paramsB<<<1, 128, 0, stream>>>(yslot, rslot, g1, b1, gr, br,
                                      bn1_a, bn1_c, bnr_a, bnr_c);
    k4_linstats<<<1024, 256, 0, stream>>>(yvp, bn1_a, bn1_c, Mslot, Sslot);
    k5_paramsC<<<1, 256, 0, stream>>>(Mslot, Sslot, wl, gl, bl, bnl_a, bnl_c);
    k6_final<<<1024, 256, 0, stream>>>(ft16, yvp, idx, rb16, packW, rww,
                                       bn1_a, bn1_c, bnl_a, bnl_c, bnr_a, bnr_c, out);
}

// Round 7
// 632.596 us; speedup vs baseline: 1.0183x; 1.0183x over previous
//
#include <hip/hip_runtime.h>

#define KNN 20
#define NN 4096
#define NPTS 32768
#define PPW 8

using short8 = __attribute__((ext_vector_type(8))) short;
using f32x4v = __attribute__((ext_vector_type(4))) float;
using uint4v = __attribute__((ext_vector_type(4))) unsigned int;
using uint2v = __attribute__((ext_vector_type(2))) unsigned int;

__device__ __forceinline__ float lrelu(float x){ return x >= 0.f ? x : 0.2f*x; }
__device__ __forceinline__ unsigned short f2b(float x){
    union { float f; unsigned u; } v; v.f = x;
    unsigned r = v.u + 0x7FFFu + ((v.u >> 16) & 1u);
    return (unsigned short)(r >> 16);
}
__device__ __forceinline__ float b2f(unsigned h){
    union { unsigned u; float f; } v; v.u = h << 16; return v.f;
}
#define WSYNC() do { asm volatile("s_waitcnt lgkmcnt(0)" ::: "memory"); __builtin_amdgcn_sched_barrier(0); } while(0)

// swizzled fragment slot: fragi*1024 + ((klocal + 16*gp) ^ (5*gp))*16
__device__ __forceinline__ int fslot(int fragi, int klocal, int gp){
    return fragi*1024 + (((klocal) + ((gp)<<4)) ^ ((gp)*5))*16;
}

// ---------------- kprep: pack weight fragments + derived weights ----------------
__global__ void kprep(const float* __restrict__ weff, const float* __restrict__ wattn,
                      const float* __restrict__ wres, const float* __restrict__ wl,
                      unsigned short* __restrict__ packW, float* __restrict__ wdiff,
                      float* __restrict__ w32t, float* __restrict__ wrb,
                      float* __restrict__ rww)
{
    __shared__ float sres[4096];   // wres[o][c]
    __shared__ float sweff[4160];  // weff[c][j]
    __shared__ float scomb[2048];  // Wcomb[o][j] = sum_c wres[o][c]*weff[c][j]
    int t = threadIdx.x;
    for (int m=t; m<4096; m+=256) sres[m] = wres[m];
    for (int m=t; m<4160; m+=256) sweff[m] = weff[m];
    __syncthreads();
    for (int q=t;q<2048;q+=256){
        int c=q>>5, j=q&31;
        wdiff[q] = sweff[c*65+33+j]-sweff[c*65+j];
    }
    if (t<64) w32t[t] = sweff[t*65+32];
    for (int q=t;q<2048;q+=256){
        int o=q>>5, j=q&31;
        float a=0.f, b=0.f;
        for (int c=0;c<64;c++){
            float wr = sres[o*64+c];
            a += wr*sweff[c*65+j];
            b += wr*(sweff[c*65+33+j]-sweff[c*65+j]);
        }
        scomb[q]=a; wrb[q]=b;
    }
    if (t<64){
        float a=0.f;
        for (int c=0;c<64;c++) a += sres[t*64+c]*sweff[c*65+32];
        rww[t]=a;
    }
    __syncthreads();
    // frags 0..23: weff(4), wattn(12), wres(8)
    for (int q = t; q < 1536; q += 256){
        int f = q >> 6, l = q & 63;
        #pragma unroll
        for (int j=0;j<8;j++){
            int koff, n; float v;
            if (f < 4){ n = f*16 + (l&15); koff = 0;
                int k = koff + (j>=4?16:0) + 4*(l>>4) + (j&3);
                v = sweff[n*65 + k];
            } else if (f < 16){ int ff=f-4; n = (ff>>1)*16 + (l&15); koff = (ff&1)*32;
                int k = koff + (j>=4?16:0) + 4*(l>>4) + (j&3);
                v = wattn[n*64 + k];
            } else { int ff=f-16; n = (ff>>1)*16 + (l&15); koff = (ff&1)*32;
                int k = koff + (j>=4?16:0) + 4*(l>>4) + (j&3);
                v = sres[n*64 + k];
            }
            packW[(size_t)(f*64+l)*8 + j] = f2b(v);
        }
    }
    // frags 24..27: Wcomb (K=32); 28..31: wl (K=16 padded)
    for (int q=t;q<512;q+=256){
        int f=q>>6, l=q&63;
        int nt = f&3; bool iswl = f>=4;
        #pragma unroll
        for (int j=0;j<8;j++){
            int kdim = (j>=4?16:0)+4*(l>>4)+(j&3);
            float v;
            if (!iswl) v = scomb[(nt*16+(l&15))*32 + kdim];
            else v = (kdim<16) ? wl[(nt*16+(l&15))*16 + kdim] : 0.f;
            packW[(size_t)((24+f)*64+l)*8+j] = f2b(v);
        }
    }
}

// ---------------- K0: tables + q/base/rb GEMV + stats ----------------
__global__ void __launch_bounds__(256) k0_prep(
    const float* __restrict__ pts, const float* __restrict__ feat,
    const float* __restrict__ wq, const float* __restrict__ wpos1,
    const float* __restrict__ wefp, const float* __restrict__ wdiff,
    const float* __restrict__ wrb,
    unsigned short* __restrict__ ft16, float* __restrict__ pt4,
    unsigned short* __restrict__ qp16, float* __restrict__ pp,
    unsigned short* __restrict__ base16, float* __restrict__ bpp,
    unsigned short* __restrict__ rb16,
    float* __restrict__ qsum, float* __restrict__ qsq,
    float* __restrict__ psum, float* __restrict__ psq)
{
    __shared__ float swq[2048];
    __shared__ float swd[2048];
    __shared__ float swr[2048];
    __shared__ float red[4][64], red2[4][64];
    int tid = threadIdx.x;
    for (int m=tid;m<2048;m+=256){ swq[m]=wq[m]; swd[m]=wdiff[m]; swr[m]=wrb[m]; }
    __syncthreads();
    int r = blockIdx.x*256 + tid;
    int b = r >> 12, n = r & 4095;
    float p0 = pts[((size_t)b*3+0)*NN+n];
    float p1 = pts[((size_t)b*3+1)*NN+n];
    float p2 = pts[((size_t)b*3+2)*NN+n];
    float pm = (p0+p1+p2)*(1.f/3.f);
    *(float4*)(pt4 + (size_t)r*4) = make_float4(p0,p1,p2,pm);
    float f[32];
    #pragma unroll
    for (int c=0;c<32;c++) f[c] = feat[((size_t)b*32+c)*NN+n];
    #pragma unroll
    for (int c=0;c<32;c+=2){
        unsigned pk = (unsigned)f2b(f[c]) | ((unsigned)f2b(f[c+1])<<16);
        *(unsigned*)(ft16 + (size_t)r*32 + c) = pk;
    }
    float q[64];
    for (int o=0;o<64;o++){
        float a=0.f;
        #pragma unroll
        for (int c=0;c<32;c++) a += swq[o*32+c]*f[c];
        q[o]=a;
    }
    for (int o=0;o<64;o+=2){
        unsigned pk = (unsigned)f2b(q[o]) | ((unsigned)f2b(q[o+1])<<16);
        *(unsigned*)(qp16 + (size_t)r*64 + o) = pk;
    }
    int lane = tid & 63, wvv = tid>>6;
    for (int o=0;o<64;o++){
        float s=q[o], s2=q[o]*q[o];
        for (int d=1; d<64; d<<=1){ s += __shfl_xor(s,d); s2 += __shfl_xor(s2,d); }
        if (lane==0){ red[wvv][o]=s; red2[wvv][o]=s2; }
    }
    __syncthreads();
    if (tid<64){
        atomicAdd(qsum+tid, red[0][tid]+red[1][tid]+red[2][tid]+red[3][tid]);
        atomicAdd(qsq+tid, red2[0][tid]+red2[1][tid]+red2[2][tid]+red2[3][tid]);
    }
    for (int o=0;o<64;o++){
        float a=0.f;
        #pragma unroll
        for (int c=0;c<32;c++) a += swd[o*32+c]*f[c];
        q[o]=a;
    }
    for (int o=0;o<64;o+=2){
        unsigned pk = (unsigned)f2b(q[o]) | ((unsigned)f2b(q[o+1])<<16);
        *(unsigned*)(base16 + (size_t)r*64 + o) = pk;
    }
    // rb = f . Wrb^T
    for (int o=0;o<64;o++){
        float a=0.f;
        #pragma unroll
        for (int c=0;c<32;c++) a += swr[o*32+c]*f[c];
        q[o]=a;
    }
    for (int o=0;o<64;o+=2){
        unsigned pk = (unsigned)f2b(q[o]) | ((unsigned)f2b(q[o+1])<<16);
        *(unsigned*)(rb16 + (size_t)r*64 + o) = pk;
    }
    float pr[8];
    #pragma unroll
    for (int o=0;o<6;o++) pr[o] = wpos1[o*3]*p0 + wpos1[o*3+1]*p1 + wpos1[o*3+2]*p2;
    pr[6]=0.f; pr[7]=0.f;
    *(float4*)(pp+(size_t)r*8)   = make_float4(pr[0],pr[1],pr[2],pr[3]);
    *(float4*)(pp+(size_t)r*8+4) = make_float4(pr[4],pr[5],pr[6],pr[7]);
    __syncthreads();
    for (int o=0;o<6;o++){
        float s=pr[o], s2=pr[o]*pr[o];
        for (int d=1;d<64;d<<=1){ s += __shfl_xor(s,d); s2 += __shfl_xor(s2,d); }
        if (lane==0){ red[wvv][o]=s; red2[wvv][o]=s2; }
    }
    __syncthreads();
    if (tid<6){
        atomicAdd(psum+tid, red[0][tid]+red[1][tid]+red[2][tid]+red[3][tid]);
        atomicAdd(psq+tid, red2[0][tid]+red2[1][tid]+red2[2][tid]+red2[3][tid]);
    }
    #pragma unroll
    for (int j=0;j<6;j++)
        bpp[(size_t)r*8+j] = p0*(wefp[j*7+4]-wefp[j*7]) + p1*(wefp[j*7+5]-wefp[j*7+1])
                           + p2*(wefp[j*7+6]-wefp[j*7+2]);
    bpp[(size_t)r*8+6]=0.f; bpp[(size_t)r*8+7]=0.f;
}

// ---------------- K1: bnq / bnp params ----------------
__global__ void k1_paramsA(
    const float* __restrict__ qsum, const float* __restrict__ qsq,
    const float* __restrict__ psum, const float* __restrict__ psq,
    const float* __restrict__ gq, const float* __restrict__ bq,
    const float* __restrict__ gp, const float* __restrict__ bp,
    float* __restrict__ bnq_a, float* __restrict__ bnq_c,
    float* __restrict__ bnp_a, float* __restrict__ bnp_c)
{
    int t = threadIdx.x;
    const float inv = 1.f/32768.f;
    if (t < 64){
        float m = qsum[t]*inv; float v = qsq[t]*inv - m*m;
        float a = gq[t]*rsqrtf(v + 1e-5f);
        bnq_a[t] = a; bnq_c[t] = bq[t] - m*a;
    }
    if (t < 6){
        float m = psum[t]*inv; float v = psq[t]*inv - m*m;
        float a = gp[t]*rsqrtf(v + 1e-5f);
        bnp_a[t] = a; bnp_c[t] = bp[t] - m*a;
    }
}

// ---------------- K2: fused attention, MFMA, pipelined wave-per-point ----------------
// LDS per-wave arena 10240 B, overlaid regions:
//  R1 [0,4096):    ANB frags 0,1 (staging) -> overwritten by ATR frags 0..3 (softmax)
//  R2 [4096,8192): KFR frags 0..3 -> overwritten by A2B rows (stride 200)
#define ARENA 10240
#define R1    0
#define R2    4096
#define SFM   8192
#define SSKP  8320
#define SIDX  8960
#define YST   9600

__global__ void __launch_bounds__(256, 3) k2_main(
    const unsigned short* __restrict__ ft16, const float* __restrict__ pt4,
    const unsigned short* __restrict__ qp16, const float* __restrict__ pp,
    const unsigned short* __restrict__ base16, const float* __restrict__ bpp,
    const int* __restrict__ idx,
    const float* __restrict__ wefp, const float* __restrict__ wpos2,
    const unsigned short* __restrict__ packW, const float* __restrict__ w32t,
    const float* __restrict__ bnq_a, const float* __restrict__ bnq_c,
    const float* __restrict__ bnp_a, const float* __restrict__ bnp_c,
    unsigned short* __restrict__ yv,
    float* __restrict__ yslot, float* __restrict__ rslot)
{
    __shared__ __align__(16) char smem_[4*ARENA];
    const int tid = threadIdx.x;
    const int l = tid & 63, wv = tid >> 6;
    const int lo = l & 15, g = l >> 4;
    char* S = smem_ + wv*ARENA;
    const int srd = (l ^ (g*5))*16;

    float w2r[4][6], w32r[4], bnqa[4], bnqc[4];
    #pragma unroll
    for (int nt=0;nt<4;nt++){
        #pragma unroll
        for (int j=0;j<6;j++) w2r[nt][j] = wpos2[(nt*16+lo)*6+j];
        w32r[nt] = w32t[nt*16+lo];
        bnqa[nt] = bnq_a[nt*16+lo];
        bnqc[nt] = bnq_c[nt*16+lo];
    }
    float bnpa[6], bnpc[6];
    #pragma unroll
    for (int j=0;j<6;j++){ bnpa[j]=bnp_a[j]; bnpc[j]=bnp_c[j]; }

    float ysum=0.f, ysq=0.f;
    float racc[4]={0.f,0.f,0.f,0.f}, rsqa[4]={0.f,0.f,0.f,0.f};

    const int rbase = blockIdx.x*(4*PPW) + wv*PPW;

    *(int*)(S+SIDX+l*4)        = idx[(size_t)rbase*KNN + l];
    *(int*)(S+SIDX+(64+l)*4)   = idx[(size_t)rbase*KNN + 64 + l];
    if (l < 32) *(int*)(S+SIDX+(128+l)*4) = idx[(size_t)rbase*KNN + 128 + l];
    WSYNC();

    uint2 ng0, ng1; uint2 ng2 = make_uint2(0u,0u); float4 ngp4 = make_float4(0,0,0,0);
    unsigned short nqr[4], nbr[4];
    float nppr[6], nbppr[6];
    float xqv[4], basev[4], sp[6];

#define ISSUE(pi_) { \
    int sb = (pi_)*KNN*4; size_t rr = (size_t)(rbase + (pi_)); \
    int i0 = *(const int*)(S+SIDX+sb+(l>>3)*4); \
    int i1 = *(const int*)(S+SIDX+sb+(8+(l>>3))*4); \
    ng0 = *(const uint2*)(ft16 + (size_t)i0*32 + (l&7)*4); \
    ng1 = *(const uint2*)(ft16 + (size_t)i1*32 + (l&7)*4); \
    if (l < 32){ int i2 = *(const int*)(S+SIDX+sb+(16+(l>>3))*4); \
                 ng2 = *(const uint2*)(ft16 + (size_t)i2*32 + (l&7)*4); } \
    if (l < KNN){ int ip = *(const int*)(S+SIDX+sb+l*4); \
                  ngp4 = *(const float4*)(pt4 + (size_t)ip*4); } \
    _Pragma("unroll") for (int nt=0;nt<4;nt++){ \
        nqr[nt] = __builtin_nontemporal_load(qp16 + rr*64 + nt*16+lo); \
        nbr[nt] = __builtin_nontemporal_load(base16 + rr*64 + nt*16+lo); } \
    _Pragma("unroll") for (int j=0;j<6;j++){ \
        nppr[j] = __builtin_nontemporal_load(pp + rr*8+j); \
        nbppr[j] = __builtin_nontemporal_load(bpp + rr*8+j); } \
    __builtin_amdgcn_sched_barrier(0); \
}

#define STAGE() { \
    float s0 = b2f(ng0.x&0xffffu)+b2f(ng0.x>>16)+b2f(ng0.y&0xffffu)+b2f(ng0.y>>16); \
    float s1 = b2f(ng1.x&0xffffu)+b2f(ng1.x>>16)+b2f(ng1.y&0xffffu)+b2f(ng1.y>>16); \
    float s2 = b2f(ng2.x&0xffffu)+b2f(ng2.x>>16)+b2f(ng2.y&0xffffu)+b2f(ng2.y>>16); \
    s0 += __shfl_xor(s0,1); s0 += __shfl_xor(s0,2); s0 += __shfl_xor(s0,4); \
    s1 += __shfl_xor(s1,1); s1 += __shfl_xor(s1,2); s1 += __shfl_xor(s1,4); \
    s2 += __shfl_xor(s2,1); s2 += __shfl_xor(s2,2); s2 += __shfl_xor(s2,4); \
    if ((l&7)==0){ \
        *(float*)(S+SFM+(l>>3)*4) = s0*(1.f/32.f); \
        *(float*)(S+SFM+(8+(l>>3))*4) = s1*(1.f/32.f); \
        if (l < 32) *(float*)(S+SFM+(16+(l>>3))*4) = s2*(1.f/32.f); \
    } \
    { int kk = l>>3, gp_ = l&3, jb = ((l>>2)&1)*8; \
      *(uint2*)(S + R1 + fslot(0, kk, gp_) + jb) = ng0; \
      *(uint2*)(S + R1 + fslot(0, 8+kk, gp_) + jb) = ng1; \
      if (l < 32) *(uint2*)(S + R1 + fslot(1, kk, gp_) + jb) = ng2; } \
    if (l < KNN){ \
        _Pragma("unroll") for (int j=0;j<6;j++){ \
            float v = nbppr[j] + wefp[j*7]*ngp4.x + wefp[j*7+1]*ngp4.y \
                    + wefp[j*7+2]*ngp4.z + wefp[j*7+3]*ngp4.w; \
            *(float*)(S+SSKP+(l*8+j)*4) = v; } } \
    _Pragma("unroll") for (int nt=0;nt<4;nt++){ \
        xqv[nt] = lrelu(bnqa[nt]*b2f(nqr[nt]) + bnqc[nt]); \
        basev[nt] = b2f(nbr[nt]); } \
    _Pragma("unroll") for (int j=0;j<6;j++) sp[j] = lrelu(bnpa[j]*nppr[j] + bnpc[j]); \
    WSYNC(); \
}

    ISSUE(0);
    STAGE();

    for (int pi=0; pi<PPW; pi++){
        const size_t r = (size_t)(rbase + pi);
        if (pi < PPW-1) ISSUE(pi+1);

        // ---- MFMA-1: kf_raw[k][c] (reads R1 ANB frags) ----
        f32x4v C1[2][4];
        #pragma unroll
        for (int mt=0;mt<2;mt++)
            #pragma unroll
            for (int nt=0;nt<4;nt++)
                #pragma unroll
                for (int i=0;i<4;i++) C1[mt][nt][i] = 0.f;
        short8 Af0 = *(const short8*)(S + R1 + 0*1024 + srd);
        short8 Af1 = *(const short8*)(S + R1 + 1*1024 + srd);
        #pragma unroll
        for (int nt=0;nt<4;nt++){
            short8 Bf = *(const short8*)(packW + (size_t)(nt*64 + l)*8);
            C1[0][nt] = __builtin_amdgcn_mfma_f32_16x16x32_bf16(Af0, Bf, C1[0][nt], 0, 0, 0);
            C1[1][nt] = __builtin_amdgcn_mfma_f32_16x16x32_bf16(Af1, Bf, C1[1][nt], 0, 0, 0);
        }
        // ---- epilogue: kf frags -> R2, attn logits ----
        #pragma unroll
        for (int mt=0;mt<2;mt++){
            #pragma unroll
            for (int i=0;i<4;i++){
                int k = mt*16 + g*4 + i;
                bool valid = (k < KNN);
                int kk = valid ? k : 0;
                float fmk = *(const float*)(S+SFM+kk*4);
                float sk[6];
                #pragma unroll
                for (int j=0;j<6;j++) sk[j] = *(const float*)(S+SSKP+(kk*8+j)*4);
                #pragma unroll
                for (int nt=0;nt<4;nt++){
                    float kf = C1[mt][nt][i] + basev[nt] + w32r[nt]*fmk;
                    if (valid){
                        int fa = fslot(mt*2+(nt>>1), g*4+i, lo>>2) + ((nt&1)*4 + (lo&3))*2;
                        *(unsigned short*)(S + R2 + fa) = f2b(kf);
                    }
                    float pos = 0.f;
                    #pragma unroll
                    for (int j=0;j<6;j++) pos += (sp[j]-sk[j])*w2r[nt][j];
                    C1[mt][nt][i] = valid ? (xqv[nt] - kf + pos)*0.125f : -1e30f;
                }
            }
        }
        // ---- softmax over k per channel; attn frags -> R1 ----
        #pragma unroll
        for (int nt=0;nt<4;nt++){
            float mx = -1e30f;
            #pragma unroll
            for (int mt=0;mt<2;mt++)
                #pragma unroll
                for (int i=0;i<4;i++) mx = fmaxf(mx, C1[mt][nt][i]);
            mx = fmaxf(mx, __shfl_xor(mx,16));
            mx = fmaxf(mx, __shfl_xor(mx,32));
            float sm = 0.f;
            #pragma unroll
            for (int mt=0;mt<2;mt++)
                #pragma unroll
                for (int i=0;i<4;i++){ float e = __expf(C1[mt][nt][i]-mx); C1[mt][nt][i]=e; sm += e; }
            sm += __shfl_xor(sm,16);
            sm += __shfl_xor(sm,32);
            float inv = 1.f/sm;
            #pragma unroll
            for (int mt=0;mt<2;mt++)
                #pragma unroll
                for (int i=0;i<4;i++){
                    int k = mt*16 + g*4 + i;
                    if (k < KNN){
                        int fa = fslot(mt*2+(nt>>1), g*4+i, lo>>2) + ((nt&1)*4 + (lo&3))*2;
                        *(unsigned short*)(S + R1 + fa) = f2b(C1[mt][nt][i]*inv);
                    }
                }
        }
        WSYNC();
        // ---- MFMA-3 (reads R2 KFR) + MFMA-2 (reads R1 ATR): one cluster ----
        short8 Ak[2][2], Aa[2][2];
        #pragma unroll
        for (int mt=0;mt<2;mt++)
            #pragma unroll
            for (int s=0;s<2;s++){
                Ak[mt][s] = *(const short8*)(S + R2 + (mt*2+s)*1024 + srd);
                Aa[mt][s] = *(const short8*)(S + R1 + (mt*2+s)*1024 + srd);
            }
        f32x4v C3[2][4];
        #pragma unroll
        for (int mt=0;mt<2;mt++)
            #pragma unroll
            for (int nt=0;nt<4;nt++)
                #pragma unroll
                for (int i=0;i<4;i++) C3[mt][nt][i] = 0.f;
        #pragma unroll
        for (int nt=0;nt<4;nt++){
            #pragma unroll
            for (int s=0;s<2;s++){
                short8 Bf = *(const short8*)(packW + (size_t)((16+nt*2+s)*64 + l)*8);
                #pragma unroll
                for (int mt=0;mt<2;mt++)
                    C3[mt][nt] = __builtin_amdgcn_mfma_f32_16x16x32_bf16(Ak[mt][s], Bf, C3[mt][nt], 0, 0, 0);
            }
        }
        f32x4v C2[2][6];
        #pragma unroll
        for (int mt=0;mt<2;mt++)
            #pragma unroll
            for (int nt=0;nt<6;nt++)
                #pragma unroll
                for (int i=0;i<4;i++) C2[mt][nt][i] = 0.f;
        #pragma unroll
        for (int nt=0;nt<6;nt++){
            #pragma unroll
            for (int s=0;s<2;s++){
                short8 Bf = *(const short8*)(packW + (size_t)((4+nt*2+s)*64 + l)*8);
                #pragma unroll
                for (int mt=0;mt<2;mt++)
                    C2[mt][nt] = __builtin_amdgcn_mfma_f32_16x16x32_bf16(Aa[mt][s], Bf, C2[mt][nt], 0, 0, 0);
            }
        }
        // ---- rf stats from C3 (regs only) ----
        #pragma unroll
        for (int mt=0;mt<2;mt++)
            #pragma unroll
            for (int i=0;i<4;i++){
                int k = mt*16 + g*4 + i;
                if (k < KNN){
                    #pragma unroll
                    for (int nt=0;nt<4;nt++){
                        float v = C3[mt][nt][i];
                        racc[nt] += v; rsqa[nt] += v*v;
                    }
                }
            }
        // ---- A2B rows -> R2 (stride 200) ----
        #pragma unroll
        for (int mt=0;mt<2;mt++)
            #pragma unroll
            for (int nt=0;nt<6;nt++)
                #pragma unroll
                for (int i=0;i<4;i++){
                    int k = mt*16 + g*4 + i;
                    if (k < KNN)
                        *(unsigned short*)(S + R2 + k*200 + (nt*16+lo)*2) = f2b(C2[mt][nt][i]);
                }
        WSYNC();
        // ---- y[k][h] ----
        #pragma unroll
        for (int it=0; it<5; it++){
            int kq = it*4 + g;
            const char* row = S + R2 + kq*200 + lo*12;
            unsigned d0 = *(const unsigned*)(row);
            unsigned d1 = *(const unsigned*)(row+4);
            unsigned d2 = *(const unsigned*)(row+8);
            float yval = b2f(d0&0xffffu) * (*(const float*)(S+SSKP+(kq*8+0)*4))
                       + b2f(d0>>16)    * (*(const float*)(S+SSKP+(kq*8+1)*4))
                       + b2f(d1&0xffffu)* (*(const float*)(S+SSKP+(kq*8+2)*4))
                       + b2f(d1>>16)    * (*(const float*)(S+SSKP+(kq*8+3)*4))
                       + b2f(d2&0xffffu)* (*(const float*)(S+SSKP+(kq*8+4)*4))
                       + b2f(d2>>16)    * (*(const float*)(S+SSKP+(kq*8+5)*4));
            *(unsigned short*)(S + YST + kq*32 + lo*2) = f2b(yval);
            ysum += yval; ysq += yval*yval;
        }
        WSYNC();
        // ---- coalesced yv store (nt: single-touch stream) ----
        if (l < 40){
            uint4v v = *(const uint4v*)(S + YST + l*16);
            __builtin_nontemporal_store(v, (uint4v*)((char*)yv + r*640 + l*16));
        }
        if (pi < PPW-1) STAGE();
    }
    // ---- stats reduce + atomics ----
    ysum += __shfl_xor(ysum,16); ysum += __shfl_xor(ysum,32);
    ysq  += __shfl_xor(ysq,16);  ysq  += __shfl_xor(ysq,32);
    #pragma unroll
    for (int nt=0;nt<4;nt++){
        racc[nt] += __shfl_xor(racc[nt],16); racc[nt] += __shfl_xor(racc[nt],32);
        rsqa[nt] += __shfl_xor(rsqa[nt],16); rsqa[nt] += __shfl_xor(rsqa[nt],32);
    }
    int slot = (blockIdx.x*4 + wv) & 63;
    if (l < 16){
        atomicAdd(yslot + slot*32 + l, ysum);
        #pragma unroll
        for (int nt=0;nt<4;nt++) atomicAdd(rslot + slot*128 + nt*16 + l, racc[nt]);
    } else if (l < 32){
        atomicAdd(yslot + slot*32 + 16 + lo, ysq);
        #pragma unroll
        for (int nt=0;nt<4;nt++) atomicAdd(rslot + slot*128 + 64 + nt*16 + lo, rsqa[nt]);
    }
#undef ISSUE
#undef STAGE
}

// ---------------- K3: bn1 (y) + bnres params ----------------
__global__ void k3_paramsB(
    const float* __restrict__ yslot, const float* __restrict__ rslot,
    const float* __restrict__ g1, const float* __restrict__ b1,
    const float* __restrict__ gr, const float* __restrict__ br,
    float* __restrict__ bn1_a, float* __restrict__ bn1_c,
    float* __restrict__ bnr_a, float* __restrict__ bnr_c)
{
    __shared__ float sy[32];
    __shared__ float sr[128];
    int t = threadIdx.x; // 128
    float s1 = 0.f;
    if (t < 32){ for (int i=0;i<64;i++) s1 += yslot[(size_t)i*32+t]; }
    float s2 = 0.f;
    for (int i=0;i<64;i++) s2 += rslot[(size_t)i*128+t];
    if (t < 32) sy[t] = s1;
    sr[t] = s2;
    __syncthreads();
    const float inv = 1.f/655360.f;
    if (t < 16){
        float m = sy[t]*inv; float v = sy[16+t]*inv - m*m;
        float a = g1[t]*rsqrtf(v + 1e-5f);
        bn1_a[t] = a; bn1_c[t] = b1[t] - m*a;
    }
    if (t < 64){
        float m = sr[t]*inv; float v = sr[64+t]*inv - m*m;
        float a = gr[t]*rsqrtf(v + 1e-5f);
        bnr_a[t] = a; bnr_c[t] = br[t] - m*a;
    }
}

// ---------------- K4: lin stats via second-moment MFMA ----------------
__global__ void __launch_bounds__(256) k4_linstats(
    const unsigned short* __restrict__ yv,
    const float* __restrict__ bn1_a, const float* __restrict__ bn1_c,
    float* __restrict__ Mslot, float* __restrict__ Sslot)
{
    __shared__ __align__(16) char lds[4*1024];
    const int tid = threadIdx.x, l = tid & 63, wvv = tid >> 6;
    const int lo = l & 15, g = l >> 4;
    char* L = lds + wvv*1024;
    const int h0 = (l&1)*8;
    float a8[8], c8[8];
    #pragma unroll
    for (int j=0;j<8;j++){ a8[j]=bn1_a[h0+j]; c8[j]=bn1_c[h0+j]; }
    short8 ones;
    #pragma unroll
    for (int j=0;j<8;j++) ones[j] = (short)0x3F80;
    f32x4v Macc, Sacc;
    #pragma unroll
    for (int i=0;i<4;i++){ Macc[i]=0.f; Sacc[i]=0.f; }
    const int waveid = blockIdx.x*4 + wvv;
    for (int it=0; it<5; it++){
        size_t s0 = ((size_t)waveid*5 + it)*32;
        uint4 v = *(const uint4*)(yv + s0*16 + l*8);
        unsigned short e0 = v.x&0xffffu, e1 = v.x>>16, e2 = v.y&0xffffu, e3 = v.y>>16;
        unsigned short e4 = v.z&0xffffu, e5 = v.z>>16, e6 = v.w&0xffffu, e7 = v.w>>16;
        float y0 = lrelu(a8[0]*b2f(e0)+c8[0]), y1 = lrelu(a8[1]*b2f(e1)+c8[1]);
        float y2_ = lrelu(a8[2]*b2f(e2)+c8[2]), y3 = lrelu(a8[3]*b2f(e3)+c8[3]);
        float y4 = lrelu(a8[4]*b2f(e4)+c8[4]), y5 = lrelu(a8[5]*b2f(e5)+c8[5]);
        float y6 = lrelu(a8[6]*b2f(e6)+c8[6]), y7 = lrelu(a8[7]*b2f(e7)+c8[7]);
        uint4 o;
        o.x = (unsigned)f2b(y0) | ((unsigned)f2b(y1)<<16);
        o.y = (unsigned)f2b(y2_)| ((unsigned)f2b(y3)<<16);
        o.z = (unsigned)f2b(y4) | ((unsigned)f2b(y5)<<16);
        o.w = (unsigned)f2b(y6) | ((unsigned)f2b(y7)<<16);
        *(uint4*)(L + l*16) = o;
        WSYNC();
        short8 Af;
        #pragma unroll
        for (int j=0;j<8;j++){
            int s = 4*g + (j&3) + ((j>=4)?16:0);
            Af[j] = *(const short*)(L + s*32 + lo*2);
        }
        WSYNC();
        Macc = __builtin_amdgcn_mfma_f32_16x16x32_bf16(Af, Af, Macc, 0, 0, 0);
        Sacc = __builtin_amdgcn_mfma_f32_16x16x32_bf16(ones, Af, Sacc, 0, 0, 0);
    }
    float* Ms = Mslot + (size_t)(waveid&15)*256;
    #pragma unroll
    for (int i=0;i<4;i++) atomicAdd(Ms + (g*4+i)*16 + lo, Macc[i]);
    if (l < 16) atomicAdd(Sslot + (size_t)(waveid&15)*16 + lo, Sacc[0]);
}

// ---------------- K5: bnlin params from M/S ----------------
__global__ void k5_paramsC(
    const float* __restrict__ Mslot, const float* __restrict__ Sslot,
    const float* __restrict__ wl,
    const float* __restrict__ gl, const float* __restrict__ bl,
    float* __restrict__ bnl_a, float* __restrict__ bnl_c)
{
    __shared__ float Ms[256], Ss[16];
    int t = threadIdx.x; // 256
    float m = 0.f;
    for (int i=0;i<16;i++) m += Mslot[(size_t)i*256+t];
    Ms[t] = m;
    if (t < 16){
        float s = 0.f;
        for (int i=0;i<16;i++) s += Sslot[(size_t)i*16+t];
        Ss[t] = s;
    }
    __syncthreads();
    if (t < 64){
        float w[16];
        #pragma unroll
        for (int h=0;h<16;h++) w[h] = wl[t*16+h];
        float lsum = 0.f;
        #pragma unroll
        for (int h=0;h<16;h++) lsum += w[h]*Ss[h];
        float lsq = 0.f;
        for (int h1=0;h1<16;h1++){
            float acc = 0.f;
            #pragma unroll
            for (int h2=0;h2<16;h2++) acc += Ms[h1*16+h2]*w[h2];
            lsq += w[h1]*acc;
        }
        const float inv = 1.f/655360.f;
        float mean = lsum*inv; float var = lsq*inv - mean*mean;
        float a = gl[t]*rsqrtf(var + 1e-5f);
        bnl_a[t] = a; bnl_c[t] = bl[t] - mean*a;
    }
}

// ---------------- K6: recompute rv + lv, combine + max over k ----------------
#define ARENA6 2848
#define SFM6 2048
#define SIDX6 2176

__global__ void __launch_bounds__(256) k6_final(
    const unsigned short* __restrict__ ft16, const unsigned short* __restrict__ yv,
    const int* __restrict__ idx, const unsigned short* __restrict__ rb16,
    const unsigned short* __restrict__ packW, const float* __restrict__ rww,
    const float* __restrict__ bn1_a, const float* __restrict__ bn1_c,
    const float* __restrict__ bnl_a, const float* __restrict__ bnl_c,
    const float* __restrict__ bnr_a, const float* __restrict__ bnr_c,
    float* __restrict__ out)
{
    __shared__ __align__(16) char smem_[4*ARENA6];
    __shared__ float sval[64*36];
    const int tid = threadIdx.x;
    const int l = tid & 63, wv = tid >> 6;
    const int lo = l & 15, g = l >> 4;
    char* S = smem_ + wv*ARENA6;
    const int srd = (l ^ (g*5))*16;

    short8 Bc[4], Bl[4];
    #pragma unroll
    for (int nt=0;nt<4;nt++){
        Bc[nt] = *(const short8*)(packW + (size_t)((24+nt)*64+l)*8);
        Bl[nt] = *(const short8*)(packW + (size_t)((28+nt)*64+l)*8);
    }
    float4 b1a = *(const float4*)(bn1_a + 4*g);
    float4 b1c = *(const float4*)(bn1_c + 4*g);
    float la[4], lc[4], ra[4], rc[4], rwv[4];
    #pragma unroll
    for (int nt=0;nt<4;nt++){
        int o = nt*16+lo;
        la[nt]=bnl_a[o]; lc[nt]=bnl_c[o]; ra[nt]=bnr_a[o]; rc[nt]=bnr_c[o]; rwv[nt]=rww[o];
    }
    const int rbase = blockIdx.x*32 + wv*8;
    *(int*)(S+SIDX6+l*4)      = idx[(size_t)rbase*KNN + l];
    *(int*)(S+SIDX6+(64+l)*4) = idx[(size_t)rbase*KNN + 64 + l];
    if (l < 32) *(int*)(S+SIDX6+(128+l)*4) = idx[(size_t)rbase*KNN + 128 + l];
    WSYNC();

    uint2 ng0, ng1; uint2 ng2 = make_uint2(0u,0u);
    uint2v ylo_ = {0u,0u}, yhi_ = {0u,0u};
    unsigned short rbr[4];
    short8 AlyA, AlyB; float rbv[4];

#define ISSUE6(pi_) { \
    int sb = (pi_)*KNN*4; size_t rr = (size_t)(rbase + (pi_)); \
    int i0 = *(const int*)(S+SIDX6+sb+(l>>3)*4); \
    int i1 = *(const int*)(S+SIDX6+sb+(8+(l>>3))*4); \
    ng0 = *(const uint2*)(ft16 + (size_t)i0*32 + (l&7)*4); \
    ng1 = *(const uint2*)(ft16 + (size_t)i1*32 + (l&7)*4); \
    if (l < 32){ int i2 = *(const int*)(S+SIDX6+sb+(16+(l>>3))*4); \
                 ng2 = *(const uint2*)(ft16 + (size_t)i2*32 + (l&7)*4); } \
    ylo_ = __builtin_nontemporal_load((const uint2v*)(yv + rr*320 + (l&15)*16 + g*4)); \
    yhi_[0] = 0u; yhi_[1] = 0u; \
    if (lo < 4) yhi_ = __builtin_nontemporal_load((const uint2v*)(yv + rr*320 + (16+(l&15))*16 + g*4)); \
    _Pragma("unroll") for (int nt=0;nt<4;nt++) \
        rbr[nt] = __builtin_nontemporal_load(rb16 + rr*64 + nt*16+lo); \
    __builtin_amdgcn_sched_barrier(0); \
}

#define STAGE6() { \
    float s0 = b2f(ng0.x&0xffffu)+b2f(ng0.x>>16)+b2f(ng0.y&0xffffu)+b2f(ng0.y>>16); \
    float s1 = b2f(ng1.x&0xffffu)+b2f(ng1.x>>16)+b2f(ng1.y&0xffffu)+b2f(ng1.y>>16); \
    float s2 = b2f(ng2.x&0xffffu)+b2f(ng2.x>>16)+b2f(ng2.y&0xffffu)+b2f(ng2.y>>16); \
    s0 += __shfl_xor(s0,1); s0 += __shfl_xor(s0,2); s0 += __shfl_xor(s0,4); \
    s1 += __shfl_xor(s1,1); s1 += __shfl_xor(s1,2); s1 += __shfl_xor(s1,4); \
    s2 += __shfl_xor(s2,1); s2 += __shfl_xor(s2,2); s2 += __shfl_xor(s2,4); \
    if ((l&7)==0){ \
        *(float*)(S+SFM6+(l>>3)*4) = s0*(1.f/32.f); \
        *(float*)(S+SFM6+(8+(l>>3))*4) = s1*(1.f/32.f); \
        if (l < 32) *(float*)(S+SFM6+(16+(l>>3))*4) = s2*(1.f/32.f); \
    } \
    { int kk = l>>3, gp_ = l&3, jb = ((l>>2)&1)*8; \
      *(uint2*)(S + fslot(0, kk, gp_) + jb) = ng0; \
      *(uint2*)(S + fslot(0, 8+kk, gp_) + jb) = ng1; \
      if (l < 32) *(uint2*)(S + fslot(1, kk, gp_) + jb) = ng2; } \
    { float t0 = lrelu(b1a.x*b2f(ylo_[0]&0xffffu)+b1c.x); \
      float t1 = lrelu(b1a.y*b2f(ylo_[0]>>16)+b1c.y); \
      float t2 = lrelu(b1a.z*b2f(ylo_[1]&0xffffu)+b1c.z); \
      float t3 = lrelu(b1a.w*b2f(ylo_[1]>>16)+b1c.w); \
      AlyA[0]=(short)f2b(t0); AlyA[1]=(short)f2b(t1); AlyA[2]=(short)f2b(t2); AlyA[3]=(short)f2b(t3); \
      AlyA[4]=0; AlyA[5]=0; AlyA[6]=0; AlyA[7]=0; \
      t0 = lrelu(b1a.x*b2f(yhi_[0]&0xffffu)+b1c.x); \
      t1 = lrelu(b1a.y*b2f(yhi_[0]>>16)+b1c.y); \
      t2 = lrelu(b1a.z*b2f(yhi_[1]&0xffffu)+b1c.z); \
      t3 = lrelu(b1a.w*b2f(yhi_[1]>>16)+b1c.w); \
      AlyB[0]=(short)f2b(t0); AlyB[1]=(short)f2b(t1); AlyB[2]=(short)f2b(t2); AlyB[3]=(short)f2b(t3); \
      AlyB[4]=0; AlyB[5]=0; AlyB[6]=0; AlyB[7]=0; } \
    _Pragma("unroll") for (int nt=0;nt<4;nt++) rbv[nt] = b2f(rbr[nt]); \
    WSYNC(); \
}

    ISSUE6(0);
    STAGE6();

    for (int pi=0; pi<8; pi++){
        if (pi < 7) ISSUE6(pi+1);
        short8 Af0 = *(const short8*)(S + 0*1024 + srd);
        short8 Af1 = *(const short8*)(S + 1*1024 + srd);
        f32x4v Crv[2][4], Clv[2][4];
        #pragma unroll
        for (int mt=0;mt<2;mt++)
            #pragma unroll
            for (int nt=0;nt<4;nt++)
                #pragma unroll
                for (int i=0;i<4;i++){ Crv[mt][nt][i]=0.f; Clv[mt][nt][i]=0.f; }
        #pragma unroll
        for (int nt=0;nt<4;nt++){
            Crv[0][nt] = __builtin_amdgcn_mfma_f32_16x16x32_bf16(Af0, Bc[nt], Crv[0][nt], 0, 0, 0);
            Crv[1][nt] = __builtin_amdgcn_mfma_f32_16x16x32_bf16(Af1, Bc[nt], Crv[1][nt], 0, 0, 0);
            Clv[0][nt] = __builtin_amdgcn_mfma_f32_16x16x32_bf16(AlyA, Bl[nt], Clv[0][nt], 0, 0, 0);
            Clv[1][nt] = __builtin_amdgcn_mfma_f32_16x16x32_bf16(AlyB, Bl[nt], Clv[1][nt], 0, 0, 0);
        }
        float vmax[4] = {-1e30f,-1e30f,-1e30f,-1e30f};
        #pragma unroll
        for (int mt=0;mt<2;mt++)
            #pragma unroll
            for (int i=0;i<4;i++){
                int k = mt*16 + g*4 + i;
                if (k < KNN){
                    float fmk = *(const float*)(S+SFM6+k*4);
                    #pragma unroll
                    for (int nt=0;nt<4;nt++){
                        float rv = Crv[mt][nt][i] + rbv[nt] + rwv[nt]*fmk;
                        float lv = Clv[mt][nt][i];
                        float val = lrelu(la[nt]*lv + lc[nt] + ra[nt]*rv + rc[nt]);
                        vmax[nt] = fmaxf(vmax[nt], val);
                    }
                }
            }
        #pragma unroll
        for (int nt=0;nt<4;nt++){
            vmax[nt] = fmaxf(vmax[nt], __shfl_xor(vmax[nt],16));
            vmax[nt] = fmaxf(vmax[nt], __shfl_xor(vmax[nt],32));
        }
        if (l < 16){
            #pragma unroll
            for (int nt=0;nt<4;nt++)
                sval[(nt*16+lo)*36 + wv*8 + pi] = vmax[nt];
        }
        if (pi < 7) STAGE6();
    }
    __syncthreads();
    // cooperative output write: 64 o x 32 pts, full 128B lines (nt stream)
    {
        int o = tid >> 2, seg = tid & 3;
        f32x4v v0 = *(const f32x4v*)(sval + o*36 + seg*8);
        f32x4v v1 = *(const f32x4v*)(sval + o*36 + seg*8 + 4);
        size_t base = ((size_t)(blockIdx.x>>7)*64 + o)*NN + (blockIdx.x&127)*32 + seg*8;
        __builtin_nontemporal_store(v0, (f32x4v*)(out + base));
        __builtin_nontemporal_store(v1, (f32x4v*)(out + base + 4));
    }
#undef ISSUE6
#undef STAGE6
}

extern "C" void kernel_launch(void* const* d_in, const int* in_sizes, int n_in,
                              void* d_out, int out_size, void* d_ws, size_t ws_size,
                              hipStream_t stream)
{
    const float* pts   = (const float*)d_in[0];
    const float* feat  = (const float*)d_in[1];
    const int*   idx   = (const int*)d_in[2];
    const float* wefp  = (const float*)d_in[3];
    const float* weff  = (const float*)d_in[4];
    const float* wq    = (const float*)d_in[5];
    const float* gq    = (const float*)d_in[6];
    const float* bq    = (const float*)d_in[7];
    const float* wpos1 = (const float*)d_in[8];
    const float* gp    = (const float*)d_in[9];
    const float* bp    = (const float*)d_in[10];
    const float* wpos2 = (const float*)d_in[11];
    const float* wattn = (const float*)d_in[12];
    const float* g1    = (const float*)d_in[13];
    const float* b1    = (const float*)d_in[14];
    const float* wl    = (const float*)d_in[15];
    const float* gl    = (const float*)d_in[16];
    const float* bl    = (const float*)d_in[17];
    const float* wres  = (const float*)d_in[18];
    const float* gr    = (const float*)d_in[19];
    const float* br    = (const float*)d_in[20];
    float* out = (float*)d_out;

    char* ws = (char*)d_ws;
    size_t o_ft16 = 0;
    size_t o_pt4  = o_ft16 + (size_t)NPTS*64;
    size_t o_qp16 = o_pt4  + (size_t)NPTS*16;
    size_t o_pp   = o_qp16 + (size_t)NPTS*128;
    size_t o_b16  = o_pp   + (size_t)NPTS*32;
    size_t o_bpp  = o_b16  + (size_t)NPTS*128;
    size_t o_rb16 = o_bpp  + (size_t)NPTS*32;
    size_t o_packW= o_rb16 + (size_t)NPTS*128;
    size_t o_wdiff= o_packW + 32*512*2;
    size_t o_wrb  = o_wdiff + 2048*4;
    size_t o_rw   = o_wrb   + 2048*4;
    size_t o_w32  = o_rw    + 64*4;
    size_t o_st   = o_w32   + 64*4;
    size_t o_qsum  = o_st;
    size_t o_qsq   = o_qsum + 64*4;
    size_t o_psum  = o_qsq  + 64*4;
    size_t o_psq   = o_psum + 8*4;
    size_t o_yslot = o_psq  + 8*4;
    size_t o_rslot = o_yslot + (size_t)64*32*4;
    size_t o_mslot = o_rslot + (size_t)64*128*4;
    size_t o_sslot = o_mslot + (size_t)16*256*4;
    size_t zero_bytes = (o_sslot + (size_t)16*16*4) - o_st;
    size_t o_par   = o_st + zero_bytes;
    size_t o_bnq_a = o_par;
    size_t o_bnq_c = o_bnq_a + 64*4;
    size_t o_bnp_a = o_bnq_c + 64*4;
    size_t o_bnp_c = o_bnp_a + 8*4;
    size_t o_bn1_a = o_bnp_c + 8*4;
    size_t o_bn1_c = o_bn1_a + 16*4;
    size_t o_bnl_a = o_bn1_c + 16*4;
    size_t o_bnl_c = o_bnl_a + 64*4;
    size_t o_bnr_a = o_bnl_c + 64*4;
    size_t o_bnr_c = o_bnr_a + 64*4;
    size_t o_yv = (o_bnr_c + 64*4 + 255) & ~(size_t)255;

    unsigned short* ft16 = (unsigned short*)(ws + o_ft16);
    float* pt4  = (float*)(ws + o_pt4);
    unsigned short* qp16 = (unsigned short*)(ws + o_qp16);
    float* ppb  = (float*)(ws + o_pp);
    unsigned short* b16p = (unsigned short*)(ws + o_b16);
    float* bppb = (float*)(ws + o_bpp);
    unsigned short* rb16 = (unsigned short*)(ws + o_rb16);
    unsigned short* packW = (unsigned short*)(ws + o_packW);
    float* wdiff= (float*)(ws + o_wdiff);
    float* wrb  = (float*)(ws + o_wrb);
    float* rww  = (float*)(ws + o_rw);
    float* w32t = (float*)(ws + o_w32);
    float* qsum = (float*)(ws + o_qsum);
    float* qsq  = (float*)(ws + o_qsq);
    float* psum = (float*)(ws + o_psum);
    float* psq  = (float*)(ws + o_psq);
    float* yslot= (float*)(ws + o_yslot);
    float* rslot= (float*)(ws + o_rslot);
    float* Mslot= (float*)(ws + o_mslot);
    float* Sslot= (float*)(ws + o_sslot);
    float* bnq_a= (float*)(ws + o_bnq_a);
    float* bnq_c= (float*)(ws + o_bnq_c);
    float* bnp_a= (float*)(ws + o_bnp_a);
    float* bnp_c= (float*)(ws + o_bnp_c);
    float* bn1_a= (float*)(ws + o_bn1_a);
    float* bn1_c= (float*)(ws + o_bn1_c);
    float* bnl_a= (float*)(ws + o_bnl_a);
    float* bnl_c= (float*)(ws + o_bnl_c);
    float* bnr_a= (float*)(ws + o_bnr_a);
    float* bnr_c= (float*)(ws + o_bnr_c);
    unsigned short* yvp = (unsigned short*)(ws + o_yv);

    (void)hipMemsetAsync(ws + o_st, 0, zero_bytes, stream);

    kprep<<<1, 256, 0, stream>>>(weff, wattn, wres, wl, packW, wdiff, w32t, wrb, rww);
    k0_prep<<<128, 256, 0, stream>>>(pts, feat, wq, wpos1, wefp, wdiff, wrb,
                                     ft16, pt4, qp16, ppb, b16p, bppb, rb16,
                                     qsum, qsq, psum, psq);
    k1_paramsA<<<1, 64, 0, stream>>>(qsum, qsq, psum, psq, gq, bq, gp, bp,
                                     bnq_a, bnq_c, bnp_a, bnp_c);
    k2_main<<<NPTS/(4*PPW), 256, 0, stream>>>(ft16, pt4, qp16, ppb, b16p, bppb, idx,
                                     wefp, wpos2, packW, w32t,
                                     bnq_a, bnq_c, bnp_a, bnp_c,
                                     yvp, yslot, rslot);
    k3_paramsB<<<1, 128, 0, stream>>>(yslot, rslot, g1, b1, gr, br,
                                      bn1_a, bn1_c, bnr_a, bnr_c);
    k4_linstats<<<1024, 256, 0, stream>>>(yvp, bn1_a, bn1_c, Mslot, Sslot);
    k5_paramsC<<<1, 256, 0, stream>>>(Mslot, Sslot, wl, gl, bl, bnl_a, bnl_c);
    k6_final<<<1024, 256, 0, stream>>>(ft16, yvp, idx, rb16, packW, rww,
                                       bn1_a, bn1_c, bnl_a, bnl_c, bnr_a, bnr_c, out);
}

// Round 8
// 480.460 us; speedup vs baseline: 1.3407x; 1.3166x over previous
//
#include <hip/hip_runtime.h>

#define KNN 20
#define NN 4096
#define NPTS 32768
#define PPW 8

using short8 = __attribute__((ext_vector_type(8))) short;
using f32x4v = __attribute__((ext_vector_type(4))) float;
using uint4v = __attribute__((ext_vector_type(4))) unsigned int;

__device__ __forceinline__ float lrelu(float x){ return x >= 0.f ? x : 0.2f*x; }
__device__ __forceinline__ unsigned short f2b(float x){
    union { float f; unsigned u; } v; v.f = x;
    unsigned r = v.u + 0x7FFFu + ((v.u >> 16) & 1u);
    return (unsigned short)(r >> 16);
}
__device__ __forceinline__ float b2f(unsigned h){
    union { unsigned u; float f; } v; v.u = h << 16; return v.f;
}
#define WSYNC() do { asm volatile("s_waitcnt lgkmcnt(0)" ::: "memory"); __builtin_amdgcn_sched_barrier(0); } while(0)

// swizzled fragment slot: fragi*1024 + ((klocal + 16*gp) ^ (5*gp))*16
__device__ __forceinline__ int fslot(int fragi, int klocal, int gp){
    return fragi*1024 + (((klocal) + ((gp)<<4)) ^ ((gp)*5))*16;
}

// ---------------- kprep: pack weight fragments + derived weights ----------------
__global__ void kprep(const float* __restrict__ weff, const float* __restrict__ wattn,
                      const float* __restrict__ wres, const float* __restrict__ wl,
                      unsigned short* __restrict__ packW, float* __restrict__ wdiff,
                      float* __restrict__ w32t, float* __restrict__ wrb,
                      float* __restrict__ rww)
{
    __shared__ float sres[4096];   // wres[o][c]
    __shared__ float sweff[4160];  // weff[c][j]
    __shared__ float scomb[2048];  // Wcomb[o][j] = sum_c wres[o][c]*weff[c][j]
    int t = threadIdx.x;
    for (int m=t; m<4096; m+=256) sres[m] = wres[m];
    for (int m=t; m<4160; m+=256) sweff[m] = weff[m];
    __syncthreads();
    for (int q=t;q<2048;q+=256){
        int c=q>>5, j=q&31;
        wdiff[q] = sweff[c*65+33+j]-sweff[c*65+j];
    }
    if (t<64) w32t[t] = sweff[t*65+32];
    for (int q=t;q<2048;q+=256){
        int o=q>>5, j=q&31;
        float a=0.f, b=0.f;
        for (int c=0;c<64;c++){
            float wr = sres[o*64+c];
            a += wr*sweff[c*65+j];
            b += wr*(sweff[c*65+33+j]-sweff[c*65+j]);
        }
        scomb[q]=a; wrb[q]=b;
    }
    if (t<64){
        float a=0.f;
        for (int c=0;c<64;c++) a += sres[t*64+c]*sweff[c*65+32];
        rww[t]=a;
    }
    __syncthreads();
    // frags 0..23: weff(4), wattn(12), wres(8)
    for (int q = t; q < 1536; q += 256){
        int f = q >> 6, l = q & 63;
        #pragma unroll
        for (int j=0;j<8;j++){
            int koff, n; float v;
            if (f < 4){ n = f*16 + (l&15); koff = 0;
                int k = koff + (j>=4?16:0) + 4*(l>>4) + (j&3);
                v = sweff[n*65 + k];
            } else if (f < 16){ int ff=f-4; n = (ff>>1)*16 + (l&15); koff = (ff&1)*32;
                int k = koff + (j>=4?16:0) + 4*(l>>4) + (j&3);
                v = wattn[n*64 + k];
            } else { int ff=f-16; n = (ff>>1)*16 + (l&15); koff = (ff&1)*32;
                int k = koff + (j>=4?16:0) + 4*(l>>4) + (j&3);
                v = sres[n*64 + k];
            }
            packW[(size_t)(f*64+l)*8 + j] = f2b(v);
        }
    }
    // frags 24..27: Wcomb (K=32); 28..31: wl (K=16 padded)
    for (int q=t;q<512;q+=256){
        int f=q>>6, l=q&63;
        int nt = f&3; bool iswl = f>=4;
        #pragma unroll
        for (int j=0;j<8;j++){
            int kdim = (j>=4?16:0)+4*(l>>4)+(j&3);
            float v;
            if (!iswl) v = scomb[(nt*16+(l&15))*32 + kdim];
            else v = (kdim<16) ? wl[(nt*16+(l&15))*16 + kdim] : 0.f;
            packW[(size_t)((24+f)*64+l)*8+j] = f2b(v);
        }
    }
}

// ---------------- K0: tables + q/base/rb GEMV + stats ----------------
__global__ void __launch_bounds__(256) k0_prep(
    const float* __restrict__ pts, const float* __restrict__ feat,
    const float* __restrict__ wq, const float* __restrict__ wpos1,
    const float* __restrict__ wefp, const float* __restrict__ wdiff,
    const float* __restrict__ wrb,
    unsigned short* __restrict__ ft16, float* __restrict__ pt4,
    unsigned short* __restrict__ qp16, float* __restrict__ pp,
    unsigned short* __restrict__ base16, float* __restrict__ bpp,
    unsigned short* __restrict__ rb16,
    float* __restrict__ qsum, float* __restrict__ qsq,
    float* __restrict__ psum, float* __restrict__ psq)
{
    __shared__ float swq[2048];
    __shared__ float swd[2048];
    __shared__ float swr[2048];
    __shared__ float red[4][64], red2[4][64];
    int tid = threadIdx.x;
    for (int m=tid;m<2048;m+=256){ swq[m]=wq[m]; swd[m]=wdiff[m]; swr[m]=wrb[m]; }
    __syncthreads();
    int r = blockIdx.x*256 + tid;
    int b = r >> 12, n = r & 4095;
    float p0 = pts[((size_t)b*3+0)*NN+n];
    float p1 = pts[((size_t)b*3+1)*NN+n];
    float p2 = pts[((size_t)b*3+2)*NN+n];
    float pm = (p0+p1+p2)*(1.f/3.f);
    *(float4*)(pt4 + (size_t)r*4) = make_float4(p0,p1,p2,pm);
    float f[32];
    #pragma unroll
    for (int c=0;c<32;c++) f[c] = feat[((size_t)b*32+c)*NN+n];
    #pragma unroll
    for (int c=0;c<32;c+=2){
        unsigned pk = (unsigned)f2b(f[c]) | ((unsigned)f2b(f[c+1])<<16);
        *(unsigned*)(ft16 + (size_t)r*32 + c) = pk;
    }
    float q[64];
    for (int o=0;o<64;o++){
        float a=0.f;
        #pragma unroll
        for (int c=0;c<32;c++) a += swq[o*32+c]*f[c];
        q[o]=a;
    }
    for (int o=0;o<64;o+=2){
        unsigned pk = (unsigned)f2b(q[o]) | ((unsigned)f2b(q[o+1])<<16);
        *(unsigned*)(qp16 + (size_t)r*64 + o) = pk;
    }
    int lane = tid & 63, wvv = tid>>6;
    for (int o=0;o<64;o++){
        float s=q[o], s2=q[o]*q[o];
        for (int d=1; d<64; d<<=1){ s += __shfl_xor(s,d); s2 += __shfl_xor(s2,d); }
        if (lane==0){ red[wvv][o]=s; red2[wvv][o]=s2; }
    }
    __syncthreads();
    if (tid<64){
        atomicAdd(qsum+tid, red[0][tid]+red[1][tid]+red[2][tid]+red[3][tid]);
        atomicAdd(qsq+tid, red2[0][tid]+red2[1][tid]+red2[2][tid]+red2[3][tid]);
    }
    for (int o=0;o<64;o++){
        float a=0.f;
        #pragma unroll
        for (int c=0;c<32;c++) a += swd[o*32+c]*f[c];
        q[o]=a;
    }
    for (int o=0;o<64;o+=2){
        unsigned pk = (unsigned)f2b(q[o]) | ((unsigned)f2b(q[o+1])<<16);
        *(unsigned*)(base16 + (size_t)r*64 + o) = pk;
    }
    // rb = f . Wrb^T
    for (int o=0;o<64;o++){
        float a=0.f;
        #pragma unroll
        for (int c=0;c<32;c++) a += swr[o*32+c]*f[c];
        q[o]=a;
    }
    for (int o=0;o<64;o+=2){
        unsigned pk = (unsigned)f2b(q[o]) | ((unsigned)f2b(q[o+1])<<16);
        *(unsigned*)(rb16 + (size_t)r*64 + o) = pk;
    }
    float pr[8];
    #pragma unroll
    for (int o=0;o<6;o++) pr[o] = wpos1[o*3]*p0 + wpos1[o*3+1]*p1 + wpos1[o*3+2]*p2;
    pr[6]=0.f; pr[7]=0.f;
    *(float4*)(pp+(size_t)r*8)   = make_float4(pr[0],pr[1],pr[2],pr[3]);
    *(float4*)(pp+(size_t)r*8+4) = make_float4(pr[4],pr[5],pr[6],pr[7]);
    __syncthreads();
    for (int o=0;o<6;o++){
        float s=pr[o], s2=pr[o]*pr[o];
        for (int d=1;d<64;d<<=1){ s += __shfl_xor(s,d); s2 += __shfl_xor(s2,d); }
        if (lane==0){ red[wvv][o]=s; red2[wvv][o]=s2; }
    }
    __syncthreads();
    if (tid<6){
        atomicAdd(psum+tid, red[0][tid]+red[1][tid]+red[2][tid]+red[3][tid]);
        atomicAdd(psq+tid, red2[0][tid]+red2[1][tid]+red2[2][tid]+red2[3][tid]);
    }
    #pragma unroll
    for (int j=0;j<6;j++)
        bpp[(size_t)r*8+j] = p0*(wefp[j*7+4]-wefp[j*7]) + p1*(wefp[j*7+5]-wefp[j*7+1])
                           + p2*(wefp[j*7+6]-wefp[j*7+2]);
    bpp[(size_t)r*8+6]=0.f; bpp[(size_t)r*8+7]=0.f;
}

// ---------------- K1: bnq / bnp params ----------------
__global__ void k1_paramsA(
    const float* __restrict__ qsum, const float* __restrict__ qsq,
    const float* __restrict__ psum, const float* __restrict__ psq,
    const float* __restrict__ gq, const float* __restrict__ bq,
    const float* __restrict__ gp, const float* __restrict__ bp,
    float* __restrict__ bnq_a, float* __restrict__ bnq_c,
    float* __restrict__ bnp_a, float* __restrict__ bnp_c)
{
    int t = threadIdx.x;
    const float inv = 1.f/32768.f;
    if (t < 64){
        float m = qsum[t]*inv; float v = qsq[t]*inv - m*m;
        float a = gq[t]*rsqrtf(v + 1e-5f);
        bnq_a[t] = a; bnq_c[t] = bq[t] - m*a;
    }
    if (t < 6){
        float m = psum[t]*inv; float v = psq[t]*inv - m*m;
        float a = gp[t]*rsqrtf(v + 1e-5f);
        bnp_a[t] = a; bnp_c[t] = bp[t] - m*a;
    }
}

// ---------------- K2: fused attention, MFMA, SERIAL wave-per-point ----------------
// LDS per-wave arena 10240 B, overlaid regions:
//  R1 [0,4096):    ANB frags 0,1 (staging) -> overwritten by ATR frags 0..3 (softmax)
//  R2 [4096,8192): KFR frags 0..3 -> overwritten by A2B rows (stride 200)
#define ARENA 10240
#define R1    0
#define R2    4096
#define SFM   8192
#define SSKP  8320
#define SIDX  8960
#define YST   9600

__global__ void __launch_bounds__(256, 3) k2_main(
    const unsigned short* __restrict__ ft16, const float* __restrict__ pt4,
    const unsigned short* __restrict__ qp16, const float* __restrict__ pp,
    const unsigned short* __restrict__ base16, const float* __restrict__ bpp,
    const int* __restrict__ idx,
    const float* __restrict__ wefp, const float* __restrict__ wpos2,
    const unsigned short* __restrict__ packW, const float* __restrict__ w32t,
    const float* __restrict__ bnq_a, const float* __restrict__ bnq_c,
    const float* __restrict__ bnp_a, const float* __restrict__ bnp_c,
    unsigned short* __restrict__ yv,
    float* __restrict__ yslot, float* __restrict__ rslot)
{
    __shared__ __align__(16) char smem_[4*ARENA];
    const int tid = threadIdx.x;
    const int l = tid & 63, wv = tid >> 6;
    const int lo = l & 15, g = l >> 4;
    char* S = smem_ + wv*ARENA;
    const int srd = (l ^ (g*5))*16;

    float w2r[4][6], w32r[4], bnqa[4], bnqc[4];
    #pragma unroll
    for (int nt=0;nt<4;nt++){
        #pragma unroll
        for (int j=0;j<6;j++) w2r[nt][j] = wpos2[(nt*16+lo)*6+j];
        w32r[nt] = w32t[nt*16+lo];
        bnqa[nt] = bnq_a[nt*16+lo];
        bnqc[nt] = bnq_c[nt*16+lo];
    }
    float bnpa[6], bnpc[6];
    #pragma unroll
    for (int j=0;j<6;j++){ bnpa[j]=bnp_a[j]; bnpc[j]=bnp_c[j]; }

    float ysum=0.f, ysq=0.f;
    float racc[4]={0.f,0.f,0.f,0.f}, rsqa[4]={0.f,0.f,0.f,0.f};

    const int rbase = blockIdx.x*(4*PPW) + wv*PPW;

    *(int*)(S+SIDX+l*4)        = idx[(size_t)rbase*KNN + l];
    *(int*)(S+SIDX+(64+l)*4)   = idx[(size_t)rbase*KNN + 64 + l];
    if (l < 32) *(int*)(S+SIDX+(128+l)*4) = idx[(size_t)rbase*KNN + 128 + l];
    WSYNC();

    for (int pi=0; pi<PPW; pi++){
        const size_t r = (size_t)(rbase + pi);
        float xqv[4], basev[4], sp[6];
        // ---- serial gather + stage (registers die within this scope) ----
        {
            int sb = pi*KNN*4;
            int i0 = *(const int*)(S+SIDX+sb+(l>>3)*4);
            int i1 = *(const int*)(S+SIDX+sb+(8+(l>>3))*4);
            uint2 ng0 = *(const uint2*)(ft16 + (size_t)i0*32 + (l&7)*4);
            uint2 ng1 = *(const uint2*)(ft16 + (size_t)i1*32 + (l&7)*4);
            uint2 ng2 = make_uint2(0u,0u);
            if (l < 32){
                int i2 = *(const int*)(S+SIDX+sb+(16+(l>>3))*4);
                ng2 = *(const uint2*)(ft16 + (size_t)i2*32 + (l&7)*4);
            }
            float4 ngp4 = make_float4(0,0,0,0);
            if (l < KNN){
                int ip = *(const int*)(S+SIDX+sb+l*4);
                ngp4 = *(const float4*)(pt4 + (size_t)ip*4);
            }
            float nbppr[6];
            if (l < KNN){
                #pragma unroll
                for (int j=0;j<6;j++) nbppr[j] = bpp[r*8+j];
            }
            float s0 = b2f(ng0.x&0xffffu)+b2f(ng0.x>>16)+b2f(ng0.y&0xffffu)+b2f(ng0.y>>16);
            float s1 = b2f(ng1.x&0xffffu)+b2f(ng1.x>>16)+b2f(ng1.y&0xffffu)+b2f(ng1.y>>16);
            float s2 = b2f(ng2.x&0xffffu)+b2f(ng2.x>>16)+b2f(ng2.y&0xffffu)+b2f(ng2.y>>16);
            s0 += __shfl_xor(s0,1); s0 += __shfl_xor(s0,2); s0 += __shfl_xor(s0,4);
            s1 += __shfl_xor(s1,1); s1 += __shfl_xor(s1,2); s1 += __shfl_xor(s1,4);
            s2 += __shfl_xor(s2,1); s2 += __shfl_xor(s2,2); s2 += __shfl_xor(s2,4);
            if ((l&7)==0){
                *(float*)(S+SFM+(l>>3)*4) = s0*(1.f/32.f);
                *(float*)(S+SFM+(8+(l>>3))*4) = s1*(1.f/32.f);
                if (l < 32) *(float*)(S+SFM+(16+(l>>3))*4) = s2*(1.f/32.f);
            }
            {
                int kk = l>>3, gp_ = l&3, jb = ((l>>2)&1)*8;
                *(uint2*)(S + R1 + fslot(0, kk, gp_) + jb) = ng0;
                *(uint2*)(S + R1 + fslot(0, 8+kk, gp_) + jb) = ng1;
                if (l < 32) *(uint2*)(S + R1 + fslot(1, kk, gp_) + jb) = ng2;
            }
            if (l < KNN){
                #pragma unroll
                for (int j=0;j<6;j++){
                    float v = nbppr[j] + wefp[j*7]*ngp4.x + wefp[j*7+1]*ngp4.y
                            + wefp[j*7+2]*ngp4.z + wefp[j*7+3]*ngp4.w;
                    *(float*)(S+SSKP+(l*8+j)*4) = v;
                }
            }
            #pragma unroll
            for (int nt=0;nt<4;nt++){
                xqv[nt] = lrelu(bnqa[nt]*b2f(qp16[r*64 + nt*16+lo]) + bnqc[nt]);
                basev[nt] = b2f(base16[r*64 + nt*16+lo]);
            }
            #pragma unroll
            for (int j=0;j<6;j++) sp[j] = lrelu(bnpa[j]*pp[r*8+j] + bnpc[j]);
            WSYNC();
        }

        // ---- MFMA-1: kf_raw[k][c] (reads R1 ANB frags) ----
        f32x4v C1[2][4];
        #pragma unroll
        for (int mt=0;mt<2;mt++)
            #pragma unroll
            for (int nt=0;nt<4;nt++)
                #pragma unroll
                for (int i=0;i<4;i++) C1[mt][nt][i] = 0.f;
        short8 Af0 = *(const short8*)(S + R1 + 0*1024 + srd);
        short8 Af1 = *(const short8*)(S + R1 + 1*1024 + srd);
        #pragma unroll
        for (int nt=0;nt<4;nt++){
            short8 Bf = *(const short8*)(packW + (size_t)(nt*64 + l)*8);
            C1[0][nt] = __builtin_amdgcn_mfma_f32_16x16x32_bf16(Af0, Bf, C1[0][nt], 0, 0, 0);
            C1[1][nt] = __builtin_amdgcn_mfma_f32_16x16x32_bf16(Af1, Bf, C1[1][nt], 0, 0, 0);
        }
        // ---- epilogue: kf frags -> R2, attn logits ----
        #pragma unroll
        for (int mt=0;mt<2;mt++){
            #pragma unroll
            for (int i=0;i<4;i++){
                int k = mt*16 + g*4 + i;
                bool valid = (k < KNN);
                int kk = valid ? k : 0;
                float fmk = *(const float*)(S+SFM+kk*4);
                float sk[6];
                #pragma unroll
                for (int j=0;j<6;j++) sk[j] = *(const float*)(S+SSKP+(kk*8+j)*4);
                #pragma unroll
                for (int nt=0;nt<4;nt++){
                    float kf = C1[mt][nt][i] + basev[nt] + w32r[nt]*fmk;
                    if (valid){
                        int fa = fslot(mt*2+(nt>>1), g*4+i, lo>>2) + ((nt&1)*4 + (lo&3))*2;
                        *(unsigned short*)(S + R2 + fa) = f2b(kf);
                    }
                    float pos = 0.f;
                    #pragma unroll
                    for (int j=0;j<6;j++) pos += (sp[j]-sk[j])*w2r[nt][j];
                    C1[mt][nt][i] = valid ? (xqv[nt] - kf + pos)*0.125f : -1e30f;
                }
            }
        }
        // ---- softmax over k per channel; attn frags -> R1 ----
        #pragma unroll
        for (int nt=0;nt<4;nt++){
            float mx = -1e30f;
            #pragma unroll
            for (int mt=0;mt<2;mt++)
                #pragma unroll
                for (int i=0;i<4;i++) mx = fmaxf(mx, C1[mt][nt][i]);
            mx = fmaxf(mx, __shfl_xor(mx,16));
            mx = fmaxf(mx, __shfl_xor(mx,32));
            float sm = 0.f;
            #pragma unroll
            for (int mt=0;mt<2;mt++)
                #pragma unroll
                for (int i=0;i<4;i++){ float e = __expf(C1[mt][nt][i]-mx); C1[mt][nt][i]=e; sm += e; }
            sm += __shfl_xor(sm,16);
            sm += __shfl_xor(sm,32);
            float inv = 1.f/sm;
            #pragma unroll
            for (int mt=0;mt<2;mt++)
                #pragma unroll
                for (int i=0;i<4;i++){
                    int k = mt*16 + g*4 + i;
                    if (k < KNN){
                        int fa = fslot(mt*2+(nt>>1), g*4+i, lo>>2) + ((nt&1)*4 + (lo&3))*2;
                        *(unsigned short*)(S + R1 + fa) = f2b(C1[mt][nt][i]*inv);
                    }
                }
        }
        WSYNC();
        // ---- MFMA-3 (reads R2 KFR) + MFMA-2 (reads R1 ATR): one cluster ----
        short8 Ak[2][2], Aa[2][2];
        #pragma unroll
        for (int mt=0;mt<2;mt++)
            #pragma unroll
            for (int s=0;s<2;s++){
                Ak[mt][s] = *(const short8*)(S + R2 + (mt*2+s)*1024 + srd);
                Aa[mt][s] = *(const short8*)(S + R1 + (mt*2+s)*1024 + srd);
            }
        f32x4v C3[2][4];
        #pragma unroll
        for (int mt=0;mt<2;mt++)
            #pragma unroll
            for (int nt=0;nt<4;nt++)
                #pragma unroll
                for (int i=0;i<4;i++) C3[mt][nt][i] = 0.f;
        #pragma unroll
        for (int nt=0;nt<4;nt++){
            #pragma unroll
            for (int s=0;s<2;s++){
                short8 Bf = *(const short8*)(packW + (size_t)((16+nt*2+s)*64 + l)*8);
                #pragma unroll
                for (int mt=0;mt<2;mt++)
                    C3[mt][nt] = __builtin_amdgcn_mfma_f32_16x16x32_bf16(Ak[mt][s], Bf, C3[mt][nt], 0, 0, 0);
            }
        }
        // ---- rf stats from C3 (regs only), then C3 dead ----
        #pragma unroll
        for (int mt=0;mt<2;mt++)
            #pragma unroll
            for (int i=0;i<4;i++){
                int k = mt*16 + g*4 + i;
                if (k < KNN){
                    #pragma unroll
                    for (int nt=0;nt<4;nt++){
                        float v = C3[mt][nt][i];
                        racc[nt] += v; rsqa[nt] += v*v;
                    }
                }
            }
        f32x4v C2[2][6];
        #pragma unroll
        for (int mt=0;mt<2;mt++)
            #pragma unroll
            for (int nt=0;nt<6;nt++)
                #pragma unroll
                for (int i=0;i<4;i++) C2[mt][nt][i] = 0.f;
        #pragma unroll
        for (int nt=0;nt<6;nt++){
            #pragma unroll
            for (int s=0;s<2;s++){
                short8 Bf = *(const short8*)(packW + (size_t)((4+nt*2+s)*64 + l)*8);
                #pragma unroll
                for (int mt=0;mt<2;mt++)
                    C2[mt][nt] = __builtin_amdgcn_mfma_f32_16x16x32_bf16(Aa[mt][s], Bf, C2[mt][nt], 0, 0, 0);
            }
        }
        // ---- A2B rows -> R2 (stride 200) ----
        #pragma unroll
        for (int mt=0;mt<2;mt++)
            #pragma unroll
            for (int nt=0;nt<6;nt++)
                #pragma unroll
                for (int i=0;i<4;i++){
                    int k = mt*16 + g*4 + i;
                    if (k < KNN)
                        *(unsigned short*)(S + R2 + k*200 + (nt*16+lo)*2) = f2b(C2[mt][nt][i]);
                }
        WSYNC();
        // ---- y[k][h] ----
        #pragma unroll
        for (int it=0; it<5; it++){
            int kq = it*4 + g;
            const char* row = S + R2 + kq*200 + lo*12;
            unsigned d0 = *(const unsigned*)(row);
            unsigned d1 = *(const unsigned*)(row+4);
            unsigned d2 = *(const unsigned*)(row+8);
            float yval = b2f(d0&0xffffu) * (*(const float*)(S+SSKP+(kq*8+0)*4))
                       + b2f(d0>>16)    * (*(const float*)(S+SSKP+(kq*8+1)*4))
                       + b2f(d1&0xffffu)* (*(const float*)(S+SSKP+(kq*8+2)*4))
                       + b2f(d1>>16)    * (*(const float*)(S+SSKP+(kq*8+3)*4))
                       + b2f(d2&0xffffu)* (*(const float*)(S+SSKP+(kq*8+4)*4))
                       + b2f(d2>>16)    * (*(const float*)(S+SSKP+(kq*8+5)*4));
            *(unsigned short*)(S + YST + kq*32 + lo*2) = f2b(yval);
            ysum += yval; ysq += yval*yval;
        }
        WSYNC();
        // ---- coalesced yv store (plain) ----
        if (l < 40){
            uint4v v = *(const uint4v*)(S + YST + l*16);
            *(uint4v*)((char*)yv + r*640 + l*16) = v;
        }
    }
    // ---- stats reduce + atomics ----
    ysum += __shfl_xor(ysum,16); ysum += __shfl_xor(ysum,32);
    ysq  += __shfl_xor(ysq,16);  ysq  += __shfl_xor(ysq,32);
    #pragma unroll
    for (int nt=0;nt<4;nt++){
        racc[nt] += __shfl_xor(racc[nt],16); racc[nt] += __shfl_xor(racc[nt],32);
        rsqa[nt] += __shfl_xor(rsqa[nt],16); rsqa[nt] += __shfl_xor(rsqa[nt],32);
    }
    int slot = (blockIdx.x*4 + wv) & 63;
    if (l < 16){
        atomicAdd(yslot + slot*32 + l, ysum);
        #pragma unroll
        for (int nt=0;nt<4;nt++) atomicAdd(rslot + slot*128 + nt*16 + l, racc[nt]);
    } else if (l < 32){
        atomicAdd(yslot + slot*32 + 16 + lo, ysq);
        #pragma unroll
        for (int nt=0;nt<4;nt++) atomicAdd(rslot + slot*128 + 64 + nt*16 + lo, rsqa[nt]);
    }
}

// ---------------- K3: bn1 (y) + bnres params ----------------
__global__ void k3_paramsB(
    const float* __restrict__ yslot, const float* __restrict__ rslot,
    const float* __restrict__ g1, const float* __restrict__ b1,
    const float* __restrict__ gr, const float* __restrict__ br,
    float* __restrict__ bn1_a, float* __restrict__ bn1_c,
    float* __restrict__ bnr_a, float* __restrict__ bnr_c)
{
    __shared__ float sy[32];
    __shared__ float sr[128];
    int t = threadIdx.x; // 128
    float s1 = 0.f;
    if (t < 32){ for (int i=0;i<64;i++) s1 += yslot[(size_t)i*32+t]; }
    float s2 = 0.f;
    for (int i=0;i<64;i++) s2 += rslot[(size_t)i*128+t];
    if (t < 32) sy[t] = s1;
    sr[t] = s2;
    __syncthreads();
    const float inv = 1.f/655360.f;
    if (t < 16){
        float m = sy[t]*inv; float v = sy[16+t]*inv - m*m;
        float a = g1[t]*rsqrtf(v + 1e-5f);
        bn1_a[t] = a; bn1_c[t] = b1[t] - m*a;
    }
    if (t < 64){
        float m = sr[t]*inv; float v = sr[64+t]*inv - m*m;
        float a = gr[t]*rsqrtf(v + 1e-5f);
        bnr_a[t] = a; bnr_c[t] = br[t] - m*a;
    }
}

// ---------------- K4: lin stats via second-moment MFMA ----------------
__global__ void __launch_bounds__(256) k4_linstats(
    const unsigned short* __restrict__ yv,
    const float* __restrict__ bn1_a, const float* __restrict__ bn1_c,
    float* __restrict__ Mslot, float* __restrict__ Sslot)
{
    __shared__ __align__(16) char lds[4*1024];
    const int tid = threadIdx.x, l = tid & 63, wvv = tid >> 6;
    const int lo = l & 15, g = l >> 4;
    char* L = lds + wvv*1024;
    const int h0 = (l&1)*8;
    float a8[8], c8[8];
    #pragma unroll
    for (int j=0;j<8;j++){ a8[j]=bn1_a[h0+j]; c8[j]=bn1_c[h0+j]; }
    short8 ones;
    #pragma unroll
    for (int j=0;j<8;j++) ones[j] = (short)0x3F80;
    f32x4v Macc, Sacc;
    #pragma unroll
    for (int i=0;i<4;i++){ Macc[i]=0.f; Sacc[i]=0.f; }
    const int waveid = blockIdx.x*4 + wvv;
    for (int it=0; it<5; it++){
        size_t s0 = ((size_t)waveid*5 + it)*32;
        uint4 v = *(const uint4*)(yv + s0*16 + l*8);
        unsigned short e0 = v.x&0xffffu, e1 = v.x>>16, e2 = v.y&0xffffu, e3 = v.y>>16;
        unsigned short e4 = v.z&0xffffu, e5 = v.z>>16, e6 = v.w&0xffffu, e7 = v.w>>16;
        float y0 = lrelu(a8[0]*b2f(e0)+c8[0]), y1 = lrelu(a8[1]*b2f(e1)+c8[1]);
        float y2_ = lrelu(a8[2]*b2f(e2)+c8[2]), y3 = lrelu(a8[3]*b2f(e3)+c8[3]);
        float y4 = lrelu(a8[4]*b2f(e4)+c8[4]), y5 = lrelu(a8[5]*b2f(e5)+c8[5]);
        float y6 = lrelu(a8[6]*b2f(e6)+c8[6]), y7 = lrelu(a8[7]*b2f(e7)+c8[7]);
        uint4 o;
        o.x = (unsigned)f2b(y0) | ((unsigned)f2b(y1)<<16);
        o.y = (unsigned)f2b(y2_)| ((unsigned)f2b(y3)<<16);
        o.z = (unsigned)f2b(y4) | ((unsigned)f2b(y5)<<16);
        o.w = (unsigned)f2b(y6) | ((unsigned)f2b(y7)<<16);
        *(uint4*)(L + l*16) = o;
        WSYNC();
        short8 Af;
        #pragma unroll
        for (int j=0;j<8;j++){
            int s = 4*g + (j&3) + ((j>=4)?16:0);
            Af[j] = *(const short*)(L + s*32 + lo*2);
        }
        WSYNC();
        Macc = __builtin_amdgcn_mfma_f32_16x16x32_bf16(Af, Af, Macc, 0, 0, 0);
        Sacc = __builtin_amdgcn_mfma_f32_16x16x32_bf16(ones, Af, Sacc, 0, 0, 0);
    }
    float* Ms = Mslot + (size_t)(waveid&15)*256;
    #pragma unroll
    for (int i=0;i<4;i++) atomicAdd(Ms + (g*4+i)*16 + lo, Macc[i]);
    if (l < 16) atomicAdd(Sslot + (size_t)(waveid&15)*16 + lo, Sacc[0]);
}

// ---------------- K5: bnlin params from M/S ----------------
__global__ void k5_paramsC(
    const float* __restrict__ Mslot, const float* __restrict__ Sslot,
    const float* __restrict__ wl,
    const float* __restrict__ gl, const float* __restrict__ bl,
    float* __restrict__ bnl_a, float* __restrict__ bnl_c)
{
    __shared__ float Ms[256], Ss[16];
    int t = threadIdx.x; // 256
    float m = 0.f;
    for (int i=0;i<16;i++) m += Mslot[(size_t)i*256+t];
    Ms[t] = m;
    if (t < 16){
        float s = 0.f;
        for (int i=0;i<16;i++) s += Sslot[(size_t)i*16+t];
        Ss[t] = s;
    }
    __syncthreads();
    if (t < 64){
        float w[16];
        #pragma unroll
        for (int h=0;h<16;h++) w[h] = wl[t*16+h];
        float lsum = 0.f;
        #pragma unroll
        for (int h=0;h<16;h++) lsum += w[h]*Ss[h];
        float lsq = 0.f;
        for (int h1=0;h1<16;h1++){
            float acc = 0.f;
            #pragma unroll
            for (int h2=0;h2<16;h2++) acc += Ms[h1*16+h2]*w[h2];
            lsq += w[h1]*acc;
        }
        const float inv = 1.f/655360.f;
        float mean = lsum*inv; float var = lsq*inv - mean*mean;
        float a = gl[t]*rsqrtf(var + 1e-5f);
        bnl_a[t] = a; bnl_c[t] = bl[t] - mean*a;
    }
}

// ---------------- K6: recompute rv + lv, combine + max over k ----------------
#define ARENA6 2848
#define SFM6 2048
#define SIDX6 2176

__global__ void __launch_bounds__(256) k6_final(
    const unsigned short* __restrict__ ft16, const unsigned short* __restrict__ yv,
    const int* __restrict__ idx, const unsigned short* __restrict__ rb16,
    const unsigned short* __restrict__ packW, const float* __restrict__ rww,
    const float* __restrict__ bn1_a, const float* __restrict__ bn1_c,
    const float* __restrict__ bnl_a, const float* __restrict__ bnl_c,
    const float* __restrict__ bnr_a, const float* __restrict__ bnr_c,
    float* __restrict__ out)
{
    __shared__ __align__(16) char smem_[4*ARENA6];
    __shared__ float sval[64*36];
    const int tid = threadIdx.x;
    const int l = tid & 63, wv = tid >> 6;
    const int lo = l & 15, g = l >> 4;
    char* S = smem_ + wv*ARENA6;
    const int srd = (l ^ (g*5))*16;

    short8 Bc[4], Bl[4];
    #pragma unroll
    for (int nt=0;nt<4;nt++){
        Bc[nt] = *(const short8*)(packW + (size_t)((24+nt)*64+l)*8);
        Bl[nt] = *(const short8*)(packW + (size_t)((28+nt)*64+l)*8);
    }
    float4 b1a = *(const float4*)(bn1_a + 4*g);
    float4 b1c = *(const float4*)(bn1_c + 4*g);
    float la[4], lc[4], ra[4], rc[4], rwv[4];
    #pragma unroll
    for (int nt=0;nt<4;nt++){
        int o = nt*16+lo;
        la[nt]=bnl_a[o]; lc[nt]=bnl_c[o]; ra[nt]=bnr_a[o]; rc[nt]=bnr_c[o]; rwv[nt]=rww[o];
    }
    const int rbase = blockIdx.x*32 + wv*8;
    *(int*)(S+SIDX6+l*4)      = idx[(size_t)rbase*KNN + l];
    *(int*)(S+SIDX6+(64+l)*4) = idx[(size_t)rbase*KNN + 64 + l];
    if (l < 32) *(int*)(S+SIDX6+(128+l)*4) = idx[(size_t)rbase*KNN + 128 + l];
    WSYNC();

    for (int pi=0; pi<8; pi++){
        size_t rr = (size_t)(rbase + pi);
        short8 AlyA, AlyB; float rbv[4];
        // ---- serial gather + stage ----
        {
            int sb = pi*KNN*4;
            int i0 = *(const int*)(S+SIDX6+sb+(l>>3)*4);
            int i1 = *(const int*)(S+SIDX6+sb+(8+(l>>3))*4);
            uint2 ng0 = *(const uint2*)(ft16 + (size_t)i0*32 + (l&7)*4);
            uint2 ng1 = *(const uint2*)(ft16 + (size_t)i1*32 + (l&7)*4);
            uint2 ng2 = make_uint2(0u,0u);
            if (l < 32){
                int i2 = *(const int*)(S+SIDX6+sb+(16+(l>>3))*4);
                ng2 = *(const uint2*)(ft16 + (size_t)i2*32 + (l&7)*4);
            }
            uint2 ylo_ = *(const uint2*)(yv + rr*320 + (l&15)*16 + g*4);
            uint2 yhi_ = make_uint2(0u,0u);
            if (lo < 4) yhi_ = *(const uint2*)(yv + rr*320 + (16+(l&15))*16 + g*4);
            unsigned short rbr[4];
            #pragma unroll
            for (int nt=0;nt<4;nt++) rbr[nt] = rb16[rr*64 + nt*16+lo];

            float s0 = b2f(ng0.x&0xffffu)+b2f(ng0.x>>16)+b2f(ng0.y&0xffffu)+b2f(ng0.y>>16);
            float s1 = b2f(ng1.x&0xffffu)+b2f(ng1.x>>16)+b2f(ng1.y&0xffffu)+b2f(ng1.y>>16);
            float s2 = b2f(ng2.x&0xffffu)+b2f(ng2.x>>16)+b2f(ng2.y&0xffffu)+b2f(ng2.y>>16);
            s0 += __shfl_xor(s0,1); s0 += __shfl_xor(s0,2); s0 += __shfl_xor(s0,4);
            s1 += __shfl_xor(s1,1); s1 += __shfl_xor(s1,2); s1 += __shfl_xor(s1,4);
            s2 += __shfl_xor(s2,1); s2 += __shfl_xor(s2,2); s2 += __shfl_xor(s2,4);
            if ((l&7)==0){
                *(float*)(S+SFM6+(l>>3)*4) = s0*(1.f/32.f);
                *(float*)(S+SFM6+(8+(l>>3))*4) = s1*(1.f/32.f);
                if (l < 32) *(float*)(S+SFM6+(16+(l>>3))*4) = s2*(1.f/32.f);
            }
            {
                int kk = l>>3, gp_ = l&3, jb = ((l>>2)&1)*8;
                *(uint2*)(S + fslot(0, kk, gp_) + jb) = ng0;
                *(uint2*)(S + fslot(0, 8+kk, gp_) + jb) = ng1;
                if (l < 32) *(uint2*)(S + fslot(1, kk, gp_) + jb) = ng2;
            }
            float t0 = lrelu(b1a.x*b2f(ylo_.x&0xffffu)+b1c.x);
            float t1 = lrelu(b1a.y*b2f(ylo_.x>>16)+b1c.y);
            float t2 = lrelu(b1a.z*b2f(ylo_.y&0xffffu)+b1c.z);
            float t3 = lrelu(b1a.w*b2f(ylo_.y>>16)+b1c.w);
            AlyA[0]=(short)f2b(t0); AlyA[1]=(short)f2b(t1); AlyA[2]=(short)f2b(t2); AlyA[3]=(short)f2b(t3);
            AlyA[4]=0; AlyA[5]=0; AlyA[6]=0; AlyA[7]=0;
            t0 = lrelu(b1a.x*b2f(yhi_.x&0xffffu)+b1c.x);
            t1 = lrelu(b1a.y*b2f(yhi_.x>>16)+b1c.y);
            t2 = lrelu(b1a.z*b2f(yhi_.y&0xffffu)+b1c.z);
            t3 = lrelu(b1a.w*b2f(yhi_.y>>16)+b1c.w);
            AlyB[0]=(short)f2b(t0); AlyB[1]=(short)f2b(t1); AlyB[2]=(short)f2b(t2); AlyB[3]=(short)f2b(t3);
            AlyB[4]=0; AlyB[5]=0; AlyB[6]=0; AlyB[7]=0;
            #pragma unroll
            for (int nt=0;nt<4;nt++) rbv[nt] = b2f(rbr[nt]);
            WSYNC();
        }

        short8 Af0 = *(const short8*)(S + 0*1024 + srd);
        short8 Af1 = *(const short8*)(S + 1*1024 + srd);
        f32x4v Crv[2][4], Clv[2][4];
        #pragma unroll
        for (int mt=0;mt<2;mt++)
            #pragma unroll
            for (int nt=0;nt<4;nt++)
                #pragma unroll
                for (int i=0;i<4;i++){ Crv[mt][nt][i]=0.f; Clv[mt][nt][i]=0.f; }
        #pragma unroll
        for (int nt=0;nt<4;nt++){
            Crv[0][nt] = __builtin_amdgcn_mfma_f32_16x16x32_bf16(Af0, Bc[nt], Crv[0][nt], 0, 0, 0);
            Crv[1][nt] = __builtin_amdgcn_mfma_f32_16x16x32_bf16(Af1, Bc[nt], Crv[1][nt], 0, 0, 0);
            Clv[0][nt] = __builtin_amdgcn_mfma_f32_16x16x32_bf16(AlyA, Bl[nt], Clv[0][nt], 0, 0, 0);
            Clv[1][nt] = __builtin_amdgcn_mfma_f32_16x16x32_bf16(AlyB, Bl[nt], Clv[1][nt], 0, 0, 0);
        }
        float vmax[4] = {-1e30f,-1e30f,-1e30f,-1e30f};
        #pragma unroll
        for (int mt=0;mt<2;mt++)
            #pragma unroll
            for (int i=0;i<4;i++){
                int k = mt*16 + g*4 + i;
                if (k < KNN){
                    float fmk = *(const float*)(S+SFM6+k*4);
                    #pragma unroll
                    for (int nt=0;nt<4;nt++){
                        float rv = Crv[mt][nt][i] + rbv[nt] + rwv[nt]*fmk;
                        float lv = Clv[mt][nt][i];
                        float val = lrelu(la[nt]*lv + lc[nt] + ra[nt]*rv + rc[nt]);
                        vmax[nt] = fmaxf(vmax[nt], val);
                    }
                }
            }
        #pragma unroll
        for (int nt=0;nt<4;nt++){
            vmax[nt] = fmaxf(vmax[nt], __shfl_xor(vmax[nt],16));
            vmax[nt] = fmaxf(vmax[nt], __shfl_xor(vmax[nt],32));
        }
        if (l < 16){
            #pragma unroll
            for (int nt=0;nt<4;nt++)
                sval[(nt*16+lo)*36 + wv*8 + pi] = vmax[nt];
        }
        WSYNC();
    }
    __syncthreads();
    // cooperative output write: 64 o x 32 pts, full 128B lines
    {
        int o = tid >> 2, seg = tid & 3;
        float4 v0 = *(const float4*)(sval + o*36 + seg*8);
        float4 v1 = *(const float4*)(sval + o*36 + seg*8 + 4);
        size_t base = ((size_t)(blockIdx.x>>7)*64 + o)*NN + (blockIdx.x&127)*32 + seg*8;
        *(float4*)(out + base) = v0;
        *(float4*)(out + base + 4) = v1;
    }
}

extern "C" void kernel_launch(void* const* d_in, const int* in_sizes, int n_in,
                              void* d_out, int out_size, void* d_ws, size_t ws_size,
                              hipStream_t stream)
{
    const float* pts   = (const float*)d_in[0];
    const float* feat  = (const float*)d_in[1];
    const int*   idx   = (const int*)d_in[2];
    const float* wefp  = (const float*)d_in[3];
    const float* weff  = (const float*)d_in[4];
    const float* wq    = (const float*)d_in[5];
    const float* gq    = (const float*)d_in[6];
    const float* bq    = (const float*)d_in[7];
    const float* wpos1 = (const float*)d_in[8];
    const float* gp    = (const float*)d_in[9];
    const float* bp    = (const float*)d_in[10];
    const float* wpos2 = (const float*)d_in[11];
    const float* wattn = (const float*)d_in[12];
    const float* g1    = (const float*)d_in[13];
    const float* b1    = (const float*)d_in[14];
    const float* wl    = (const float*)d_in[15];
    const float* gl    = (const float*)d_in[16];
    const float* bl    = (const float*)d_in[17];
    const float* wres  = (const float*)d_in[18];
    const float* gr    = (const float*)d_in[19];
    const float* br    = (const float*)d_in[20];
    float* out = (float*)d_out;

    char* ws = (char*)d_ws;
    size_t o_ft16 = 0;
    size_t o_pt4  = o_ft16 + (size_t)NPTS*64;
    size_t o_qp16 = o_pt4  + (size_t)NPTS*16;
    size_t o_pp   = o_qp16 + (size_t)NPTS*128;
    size_t o_b16  = o_pp   + (size_t)NPTS*32;
    size_t o_bpp  = o_b16  + (size_t)NPTS*128;
    size_t o_rb16 = o_bpp  + (size_t)NPTS*32;
    size_t o_packW= o_rb16 + (size_t)NPTS*128;
    size_t o_wdiff= o_packW + 32*512*2;
    size_t o_wrb  = o_wdiff + 2048*4;
    size_t o_rw   = o_wrb   + 2048*4;
    size_t o_w32  = o_rw    + 64*4;
    size_t o_st   = o_w32   + 64*4;
    size_t o_qsum  = o_st;
    size_t o_qsq   = o_qsum + 64*4;
    size_t o_psum  = o_qsq  + 64*4;
    size_t o_psq   = o_psum + 8*4;
    size_t o_yslot = o_psq  + 8*4;
    size_t o_rslot = o_yslot + (size_t)64*32*4;
    size_t o_mslot = o_rslot + (size_t)64*128*4;
    size_t o_sslot = o_mslot + (size_t)16*256*4;
    size_t zero_bytes = (o_sslot + (size_t)16*16*4) - o_st;
    size_t o_par   = o_st + zero_bytes;
    size_t o_bnq_a = o_par;
    size_t o_bnq_c = o_bnq_a + 64*4;
    size_t o_bnp_a = o_bnq_c + 64*4;
    size_t o_bnp_c = o_bnp_a + 8*4;
    size_t o_bn1_a = o_bnp_c + 8*4;
    size_t o_bn1_c = o_bn1_a + 16*4;
    size_t o_bnl_a = o_bn1_c + 16*4;
    size_t o_bnl_c = o_bnl_a + 64*4;
    size_t o_bnr_a = o_bnl_c + 64*4;
    size_t o_bnr_c = o_bnr_a + 64*4;
    size_t o_yv = (o_bnr_c + 64*4 + 255) & ~(size_t)255;

    unsigned short* ft16 = (unsigned short*)(ws + o_ft16);
    float* pt4  = (float*)(ws + o_pt4);
    unsigned short* qp16 = (unsigned short*)(ws + o_qp16);
    float* ppb  = (float*)(ws + o_pp);
    unsigned short* b16p = (unsigned short*)(ws + o_b16);
    float* bppb = (float*)(ws + o_bpp);
    unsigned short* rb16 = (unsigned short*)(ws + o_rb16);
    unsigned short* packW = (unsigned short*)(ws + o_packW);
    float* wdiff= (float*)(ws + o_wdiff);
    float* wrb  = (float*)(ws + o_wrb);
    float* rww  = (float*)(ws + o_rw);
    float* w32t = (float*)(ws + o_w32);
    float* qsum = (float*)(ws + o_qsum);
    float* qsq  = (float*)(ws + o_qsq);
    float* psum = (float*)(ws + o_psum);
    float* psq  = (float*)(ws + o_psq);
    float* yslot= (float*)(ws + o_yslot);
    float* rslot= (float*)(ws + o_rslot);
    float* Mslot= (float*)(ws + o_mslot);
    float* Sslot= (float*)(ws + o_sslot);
    float* bnq_a= (float*)(ws + o_bnq_a);
    float* bnq_c= (float*)(ws + o_bnq_c);
    float* bnp_a= (float*)(ws + o_bnp_a);
    float* bnp_c= (float*)(ws + o_bnp_c);
    float* bn1_a= (float*)(ws + o_bn1_a);
    float* bn1_c= (float*)(ws + o_bn1_c);
    float* bnl_a= (float*)(ws + o_bnl_a);
    float* bnl_c= (float*)(ws + o_bnl_c);
    float* bnr_a= (float*)(ws + o_bnr_a);
    float* bnr_c= (float*)(ws + o_bnr_c);
    unsigned short* yvp = (unsigned short*)(ws + o_yv);

    (void)hipMemsetAsync(ws + o_st, 0, zero_bytes, stream);

    kprep<<<1, 256, 0, stream>>>(weff, wattn, wres, wl, packW, wdiff, w32t, wrb, rww);
    k0_prep<<<128, 256, 0, stream>>>(pts, feat, wq, wpos1, wefp, wdiff, wrb,
                                     ft16, pt4, qp16, ppb, b16p, bppb, rb16,
                                     qsum, qsq, psum, psq);
    k1_paramsA<<<1, 64, 0, stream>>>(qsum, qsq, psum, psq, gq, bq, gp, bp,
                                     bnq_a, bnq_c, bnp_a, bnp_c);
    k2_main<<<NPTS/(4*PPW), 256, 0, stream>>>(ft16, pt4, qp16, ppb, b16p, bppb, idx,
                                     wefp, wpos2, packW, w32t,
                                     bnq_a, bnq_c, bnp_a, bnp_c,
                                     yvp, yslot, rslot);
    k3_paramsB<<<1, 128, 0, stream>>>(yslot, rslot, g1, b1, gr, br,
                                      bn1_a, bn1_c, bnr_a, bnr_c);
    k4_linstats<<<1024, 256, 0, stream>>>(yvp, bn1_a, bn1_c, Mslot, Sslot);
    k5_paramsC<<<1, 256, 0, stream>>>(Mslot, Sslot, wl, gl, bl, bnl_a, bnl_c);
    k6_final<<<1024, 256, 0, stream>>>(ft16, yvp, idx, rb16, packW, rww,
                                       bn1_a, bn1_c, bnl_a, bnl_c, bnr_a, bnr_c, out);
}